// Round 9
// baseline (387.524 us; speedup 1.0000x reference)
//
#include <hip/hip_runtime.h>

typedef __attribute__((ext_vector_type(8))) short short8;
typedef __attribute__((ext_vector_type(4))) short short4v;
typedef __attribute__((ext_vector_type(4))) float floatx4;

__device__ inline ushort f2b(float f) {
    union { uint i; float f; } c; c.f = f;
    uint i = c.i;
    uint r = (i + 0x7FFFu + ((i >> 16) & 1u)) >> 16;
    return (ushort)r;
}

__device__ __forceinline__ void load_lds16(const ushort* g, ushort* l) {
    __builtin_amdgcn_global_load_lds((const __attribute__((address_space(1))) void*)g,
                                     (__attribute__((address_space(3))) void*)l, 16, 0, 0);
}

// Fused fp32->bf16 conversion of x, wq, wk, wv + RoPE cos/sin table (one launch).
__global__ __launch_bounds__(256) void cvt4_k(const float* __restrict__ x,
                                              const float* __restrict__ wq,
                                              const float* __restrict__ wk,
                                              const float* __restrict__ wv,
                                              ushort* __restrict__ xb,
                                              ushort* __restrict__ wqb,
                                              ushort* __restrict__ wkb,
                                              ushort* __restrict__ wvb,
                                              const int* __restrict__ pos,
                                              float2* __restrict__ tab) {
    const int blk = blockIdx.x;
    if (blk >= 3584) {
        const int idx = (blk - 3584) * 256 + threadIdx.x;   // 0..65535
        const int s = idx >> 5, fi = idx & 31;
        const float inv = exp2f(-(float)fi * 0.41524101186092557f);
        const float ang = (float)pos[s] * inv;
        float sn, cs;
        sincosf(ang, &sn, &cs);
        tab[idx] = make_float2(cs, sn);
        return;
    }
    const float* in; ushort* out; int base;
    if (blk < 2048)      { in = x;  out = xb;  base = blk; }
    else if (blk < 2560) { in = wq; out = wqb; base = blk - 2048; }
    else if (blk < 3072) { in = wk; out = wkb; base = blk - 2560; }
    else                 { in = wv; out = wvb; base = blk - 3072; }
    const int i = (base * 256 + threadIdx.x) * 8;
    float4 f0 = *(const float4*)(in + i);
    float4 f1 = *(const float4*)(in + i + 4);
    ushort u[8] = {f2b(f0.x), f2b(f0.y), f2b(f0.z), f2b(f0.w),
                   f2b(f1.x), f2b(f1.y), f2b(f1.z), f2b(f1.w)};
    *(uint4*)(out + i) = *(const uint4*)u;
}

__global__ __launch_bounds__(256) void cvt_k(const float* __restrict__ in,
                                             ushort* __restrict__ out, int n) {
    const int i = (blockIdx.x * 256 + threadIdx.x) * 8;
    if (i >= n) return;
    float4 f0 = *(const float4*)(in + i);
    float4 f1 = *(const float4*)(in + i + 4);
    ushort u[8] = {f2b(f0.x), f2b(f0.y), f2b(f0.z), f2b(f0.w),
                   f2b(f1.x), f2b(f1.y), f2b(f1.z), f2b(f1.w)};
    *(uint4*)(out + i) = *(const uint4*)u;
}

// 128x128 GEMM body, K=1024, BK=32, EIGHT waves (2m x 4n of 64x32 each).
// Verified 2-phase skeleton: double-buffered LDS, one __syncthreads per K-iter.
template <bool OUTF32>
__device__ __forceinline__ void gemm_body8(ushort* As, ushort* Bs,   // [2][4096] each
                                           const ushort* __restrict__ A,
                                           const ushort* __restrict__ B,
                                           void* __restrict__ C,
                                           int N, int m0, int n0,
                                           bool doRope, const float2* __restrict__ tab,
                                           float oscale) {
    const int tid = threadIdx.x;            // 0..511
    const int wave = tid >> 6, lane = tid & 63;
    const int quad = lane >> 4, l16 = lane & 15;
    const int wm = (wave >> 2) * 64, wn = (wave & 3) * 32;

    floatx4 acc[4][2] = {};

    const int rA = tid >> 2, jgA = ((tid & 3) - (rA >> 1)) & 3;
    const ushort* ga = A + (size_t)(m0 + rA) * 1024 + jgA * 8;
    const ushort* gb = B + (size_t)(n0 + rA) * 1024 + jgA * 8;

    load_lds16(ga, As + tid * 8);
    load_lds16(gb, Bs + tid * 8);
    __syncthreads();

    for (int kt = 0; kt < 32; ++kt) {
        const int cur = kt & 1;
        if (kt + 1 < 32) {
            const int nb = (cur ^ 1) * 4096;
            load_lds16(ga + (kt + 1) * 32, As + nb + tid * 8);
            load_lds16(gb + (kt + 1) * 32, Bs + nb + tid * 8);
        }
        const ushort* as = As + cur * 4096;
        const ushort* bs = Bs + cur * 4096;
        short8 af[4], bf[2];
#pragma unroll
        for (int i = 0; i < 4; ++i) {
            const int ra = wm + i * 16 + l16;
            af[i] = *(const short8*)(as + ra * 32 + (((quad + (ra >> 1)) & 3) << 3));
        }
#pragma unroll
        for (int j = 0; j < 2; ++j) {
            const int rb = wn + j * 16 + l16;
            bf[j] = *(const short8*)(bs + rb * 32 + (((quad + (rb >> 1)) & 3) << 3));
        }
#pragma unroll
        for (int mi = 0; mi < 4; ++mi)
#pragma unroll
            for (int ni = 0; ni < 2; ++ni)
                acc[mi][ni] = __builtin_amdgcn_mfma_f32_16x16x32_bf16(af[mi], bf[ni], acc[mi][ni], 0, 0, 0);
        __syncthreads();
    }
#pragma unroll
    for (int mi = 0; mi < 4; ++mi) {
        const int row = m0 + wm + mi * 16 + quad * 4;
#pragma unroll
        for (int ni = 0; ni < 2; ++ni) {
            const int col = n0 + wn + ni * 16 + l16;
            const int fi = ((wn + ni * 16 + l16) & 63) >> 1;
#pragma unroll
            for (int r = 0; r < 4; ++r) {
                float v = acc[mi][ni][r];
                if (doRope) {
                    const float other = __shfl_xor(v, 1);
                    const float2 cs = tab[((row + r) & 2047) * 32 + fi];
                    v = (col & 1) ? (other * cs.y + v * cs.x) : (v * cs.x - other * cs.y);
                }
                v *= oscale;
                if (OUTF32) ((float*)C)[(size_t)(row + r) * N + col] = v;
                else        ((ushort*)C)[(size_t)(row + r) * N + col] = f2b(v);
            }
        }
    }
}

// Fused Q/K/Vt GEMM: 768 blocks x 512 threads (8 waves). R7-verified.
__global__ __launch_bounds__(512) void gemm_qkv(const ushort* __restrict__ xb,
                                                const ushort* __restrict__ wqb,
                                                const ushort* __restrict__ wkb,
                                                const ushort* __restrict__ wvb,
                                                ushort* __restrict__ q,
                                                ushort* __restrict__ k,
                                                ushort* __restrict__ vt,
                                                const float2* __restrict__ tab) {
    __shared__ __align__(16) ushort As[8192], Bs[8192];
    const int blk = blockIdx.x;
    const int job = blk >> 8, r = blk & 255;
    const ushort *A, *B;
    ushort* C;
    int N, m0, n0;
    bool rope;
    float osc;
    if (job == 0)      { A = xb;  B = wqb; C = q;  N = 1024; m0 = (r >> 3) * 128; n0 = (r & 7) * 128; rope = true;  osc = 0.18033688011112042f; }
    else if (job == 1) { A = xb;  B = wkb; C = k;  N = 1024; m0 = (r >> 3) * 128; n0 = (r & 7) * 128; rope = true;  osc = 1.0f; }
    else               { A = wvb; B = xb;  C = vt; N = 4096; m0 = (r & 7) * 128;  n0 = (r >> 3) * 128; rope = false; osc = 1.0f; }
    gemm_body8<false>(As, Bs, A, B, C, N, m0, n0, rope, tab, osc);
}

// Output projection: C fp32 = O[4096][1024] * wo[1024][1024]^T.
// R4-verified form: 128x64 tiles, 512 blocks = 2 blocks/CU, bf16 B via cvt_k.
__global__ __launch_bounds__(256) void gemm_o(const ushort* __restrict__ A,
                                              const ushort* __restrict__ B,
                                              float* __restrict__ C) {
    __shared__ __align__(16) ushort As[8192];   // 2 bufs x 128 rows x 32 cols
    __shared__ __align__(16) ushort Bs[4096];   // 2 bufs x  64 rows x 32 cols

    const int blk = blockIdx.x;
    const int m0 = (blk >> 4) * 128, n0 = (blk & 15) * 64;

    const int tid = threadIdx.x;
    const int wave = tid >> 6, lane = tid & 63;
    const int quad = lane >> 4, l16 = lane & 15;
    const int wm = (wave >> 1) * 64, wn = (wave & 1) * 32;

    floatx4 acc[4][2] = {};

    const int cA1 = tid, cA2 = tid + 256, cBc = tid;
    const int rA1 = cA1 >> 2, jg1 = ((cA1 & 3) - (rA1 >> 1)) & 3;
    const int rA2 = cA2 >> 2, jg2 = ((cA2 & 3) - (rA2 >> 1)) & 3;
    const int rBc = cBc >> 2, jgB = ((cBc & 3) - (rBc >> 1)) & 3;
    const ushort* ga1 = A + (size_t)(m0 + rA1) * 1024 + jg1 * 8;
    const ushort* ga2 = A + (size_t)(m0 + rA2) * 1024 + jg2 * 8;
    const ushort* gb1 = B + (size_t)(n0 + rBc) * 1024 + jgB * 8;

    load_lds16(ga1, As + cA1 * 8);
    load_lds16(ga2, As + cA2 * 8);
    load_lds16(gb1, Bs + cBc * 8);
    __syncthreads();

    for (int kt = 0; kt < 32; ++kt) {
        const int cur = kt & 1;
        if (kt + 1 < 32) {
            const int nbA = (cur ^ 1) * 4096;
            const int nbB = (cur ^ 1) * 2048;
            load_lds16(ga1 + (kt + 1) * 32, As + nbA + cA1 * 8);
            load_lds16(ga2 + (kt + 1) * 32, As + nbA + cA2 * 8);
            load_lds16(gb1 + (kt + 1) * 32, Bs + nbB + cBc * 8);
        }
        const ushort* as = As + cur * 4096;
        const ushort* bs = Bs + cur * 2048;
        short8 af[4], bf[2];
#pragma unroll
        for (int i = 0; i < 4; ++i) {
            const int ra = wm + i * 16 + l16;
            af[i] = *(const short8*)(as + ra * 32 + (((quad + (ra >> 1)) & 3) << 3));
        }
#pragma unroll
        for (int j = 0; j < 2; ++j) {
            const int rb = wn + j * 16 + l16;
            bf[j] = *(const short8*)(bs + rb * 32 + (((quad + (rb >> 1)) & 3) << 3));
        }
#pragma unroll
        for (int mi = 0; mi < 4; ++mi)
#pragma unroll
            for (int ni = 0; ni < 2; ++ni)
                acc[mi][ni] = __builtin_amdgcn_mfma_f32_16x16x32_bf16(af[mi], bf[ni], acc[mi][ni], 0, 0, 0);
        __syncthreads();
    }
#pragma unroll
    for (int mi = 0; mi < 4; ++mi) {
        const int row = m0 + wm + mi * 16 + quad * 4;
#pragma unroll
        for (int ni = 0; ni < 2; ++ni) {
            const int col = n0 + wn + ni * 16 + l16;
#pragma unroll
            for (int r = 0; r < 4; ++r)
                C[(size_t)(row + r) * 1024 + col] = acc[mi][ni][r];
        }
    }
}

// Causal flash attention, SPLIT-K. T = max_steps x step_latency (R8 lesson), so
// cut max_steps: tiles qt>=16 are split into two k-halves (8..16 steps each);
// qt<=15 run whole (1..16 steps). Max steps/block: 32 -> 16. Grid 1536 >
// resident 1280 -> dynamic refill, heavy-first.
// Fixed-reference softmax makes partials additive: O = (O1+O2)/(l1+l2).
// Combine: both halves atomicAdd fp32 partials into zeroed scratch, threadfence,
// bump per-tile counter; second finisher re-reads (agent scope), normalizes,
// writes bf16 Og. Order-free, no spinning (no deadlock under refill).
__global__ __launch_bounds__(256, 4) void attn_k(const ushort* __restrict__ Qg,
                                                 const ushort* __restrict__ Kg,
                                                 const ushort* __restrict__ Vtg,
                                                 ushort* __restrict__ Og,
                                                 float* __restrict__ Opart,
                                                 float* __restrict__ lpart,
                                                 uint* __restrict__ cnt) {
    __shared__ __align__(16) ushort Ks[2][4096];   // [s][d] chunk-swizzled
    __shared__ __align__(16) ushort Vs[2][4096];   // [d][s] chunk-swizzled
    __shared__ int lastFlag;

    const int tid = threadIdx.x;
    const int wave = tid >> 6, lane = tid & 63;
    const int quad = lane >> 4, l16 = lane & 15;
    const int blk = blockIdx.x;

    int bh, qt, k0, ks, tile;
    bool split, hasDiag;
    if (blk < 1024) {                       // split halves of qt in [16,31]
        tile = blk >> 1;
        const int half = blk & 1;
        bh = tile & 31;
        qt = 16 + (tile >> 5);
        const int nk = qt + 1, hf = nk >> 1;
        k0 = half ? hf : 0;
        ks = half ? (nk - hf) : hf;         // 8..16 steps
        hasDiag = (half == 1);
        split = true;
    } else {                                // whole tiles qt in [0,15], heavy-first
        const int idx = blk - 1024;
        bh = idx & 31;
        qt = 15 - (idx >> 5);
        k0 = 0; ks = qt + 1;                // 1..16 steps
        hasDiag = true; split = false; tile = 0;
    }
    const int b = bh >> 4, hh = bh & 15;
    const int bq = b * 2048;
    const int wl = wave * 16 + l16;        // q-row within 64-row tile

    const int cA = tid, cB = tid + 256;
    const int sA = cA >> 3, jA = ((cA & 7) - sA) & 7;
    const int sB = cB >> 3, jB = ((cB & 7) - sB) & 7;
    const ushort* kgA = Kg + (size_t)(bq + k0 * 64 + sA) * 1024 + hh * 64 + jA * 8;
    const ushort* kgB = Kg + (size_t)(bq + k0 * 64 + sB) * 1024 + hh * 64 + jB * 8;
    const ushort* vgA = Vtg + (size_t)(hh * 64 + sA) * 4096 + bq + k0 * 64 + jA * 8;
    const ushort* vgB = Vtg + (size_t)(hh * 64 + sB) * 4096 + bq + k0 * 64 + jB * 8;

    // kt-invariant LDS read offsets (ushort units)
    const int kb0 = l16 * 64 + (((quad + l16) & 7) << 3);
    const int kb1 = l16 * 64 + (((quad + 4 + l16) & 7) << 3);
    int vbs[4];
#pragma unroll
    for (int cb = 0; cb < 4; ++cb)
        vbs[cb] = l16 * 64 + (((cb * 2 + (quad >> 1) + l16) & 7) << 3) + (quad & 1) * 4;

    const ushort* qrow = Qg + (size_t)(bq + qt * 64 + wl) * 1024 + hh * 64 + quad * 8;
    const short8 qf0 = *(const short8*)qrow;
    const short8 qf1 = *(const short8*)(qrow + 32);

    floatx4 od[4] = {};
    float l_st = 0.0f;                      // per-lane partial (16 k's); shfl at end

    load_lds16(kgA, &Ks[0][cA * 8]);
    load_lds16(kgB, &Ks[0][cB * 8]);
    load_lds16(vgA, &Vs[0][cA * 8]);
    load_lds16(vgB, &Vs[0][cB * 8]);
    __syncthreads();

    const ushort* kgA2 = kgA + 65536;
    const ushort* kgB2 = kgB + 65536;
    const ushort* vgA2 = vgA + 64;
    const ushort* vgB2 = vgB + 64;

    auto step = [&](int kt, bool diag, bool pref) {
        const int cur = kt & 1;
        if (pref) {
            const int nxt = cur ^ 1;
            load_lds16(kgA2, &Ks[nxt][cA * 8]);
            load_lds16(kgB2, &Ks[nxt][cB * 8]);
            load_lds16(vgA2, &Vs[nxt][cA * 8]);
            load_lds16(vgB2, &Vs[nxt][cB * 8]);
            kgA2 += 65536; kgB2 += 65536; vgA2 += 64; vgB2 += 64;
        }
        const ushort* kc = &Ks[cur][0];
        const ushort* vc = &Vs[cur][0];

        // S^T = K Q^T  (Q pre-scaled, st already in log2 domain)
        floatx4 st[4];
        __builtin_amdgcn_s_setprio(1);
#pragma unroll
        for (int cb = 0; cb < 4; ++cb) {
            short8 kf0 = *(const short8*)(kc + kb0 + cb * 1024);
            short8 kf1 = *(const short8*)(kc + kb1 + cb * 1024);
            floatx4 z = {};
            z = __builtin_amdgcn_mfma_f32_16x16x32_bf16(kf0, qf0, z, 0, 0, 0);
            z = __builtin_amdgcn_mfma_f32_16x16x32_bf16(kf1, qf1, z, 0, 0, 0);
            st[cb] = z;
        }
        __builtin_amdgcn_s_setprio(0);

        float pv[4][4];
        float sum = 0.0f;
#pragma unroll
        for (int cb = 0; cb < 4; ++cb) {
            const int scb = cb * 16 + quad * 4;
#pragma unroll
            for (int r = 0; r < 4; ++r) {
                float e = exp2f(st[cb][r]);
                if (diag && (scb + r > wl)) e = 0.0f;
                pv[cb][r] = e;
                sum += e;
            }
        }
        l_st += sum;                        // lane partial; cross-quad shfl deferred

        short4v pb[4];
#pragma unroll
        for (int cb = 0; cb < 4; ++cb) {
            uint lo_, hi_;
            asm("v_cvt_pk_bf16_f32 %0, %1, %2" : "=v"(lo_) : "v"(pv[cb][0]), "v"(pv[cb][1]));
            asm("v_cvt_pk_bf16_f32 %0, %1, %2" : "=v"(hi_) : "v"(pv[cb][2]), "v"(pv[cb][3]));
            union { uint u[2]; short4v s; } cvu;
            cvu.u[0] = lo_; cvu.u[1] = hi_;
            pb[cb] = cvu.s;
        }

        __builtin_amdgcn_s_setprio(1);
#pragma unroll
        for (int db = 0; db < 4; ++db) {
#pragma unroll
            for (int cb = 0; cb < 4; ++cb) {
                short4v vf = *(const short4v*)(vc + vbs[cb] + db * 1024);
                od[db] = __builtin_amdgcn_mfma_f32_16x16x16bf16_1k(vf, pb[cb], od[db], 0, 0, 0);
            }
        }
        __builtin_amdgcn_s_setprio(0);
        if (pref) __syncthreads();   // protect buffer reuse; last iter skips
    };

    for (int s = 0; s < ks - 1; ++s) step(s, false, true);
    step(ks - 1, hasDiag, false);           // diag mask only on the owning half

    // cross-quad row reduction (once, off the per-step critical path)
    l_st += __shfl_xor(l_st, 16);
    l_st += __shfl_xor(l_st, 32);

    if (!split) {
        const float linv = 1.0f / l_st;
        ushort* orow = Og + (size_t)(bq + qt * 64 + wl) * 1024 + hh * 64 + quad * 4;
#pragma unroll
        for (int db = 0; db < 4; ++db) {
            uint2 w;
            w.x = (uint)f2b(od[db][0] * linv) | ((uint)f2b(od[db][1] * linv) << 16);
            w.y = (uint)f2b(od[db][2] * linv) | ((uint)f2b(od[db][3] * linv) << 16);
            *(uint2*)(orow + db * 16) = w;
        }
    } else {
        // additive combine into zeroed fp32 scratch
        float* op = Opart + (size_t)tile * 4096 + wl * 64 + quad * 4;
#pragma unroll
        for (int db = 0; db < 4; ++db)
#pragma unroll
            for (int r = 0; r < 4; ++r)
                atomicAdd(op + db * 16 + r, od[db][r]);
        if (quad == 0) atomicAdd(lpart + tile * 64 + wl, l_st);
        __threadfence();
        if (tid == 0) lastFlag = (int)(atomicAdd(cnt + tile, 1u) == 1u);
        __syncthreads();
        if (lastFlag) {                     // second finisher normalizes + writes
            __threadfence();
            const float l = __hip_atomic_load(lpart + tile * 64 + wl,
                                              __ATOMIC_RELAXED, __HIP_MEMORY_SCOPE_AGENT);
            const float linv = 1.0f / l;
            const float* rp = Opart + (size_t)tile * 4096 + wl * 64 + quad * 4;
            ushort* orow = Og + (size_t)(bq + qt * 64 + wl) * 1024 + hh * 64 + quad * 4;
#pragma unroll
            for (int db = 0; db < 4; ++db) {
                float v0 = __hip_atomic_load(rp + db * 16 + 0, __ATOMIC_RELAXED, __HIP_MEMORY_SCOPE_AGENT);
                float v1 = __hip_atomic_load(rp + db * 16 + 1, __ATOMIC_RELAXED, __HIP_MEMORY_SCOPE_AGENT);
                float v2 = __hip_atomic_load(rp + db * 16 + 2, __ATOMIC_RELAXED, __HIP_MEMORY_SCOPE_AGENT);
                float v3 = __hip_atomic_load(rp + db * 16 + 3, __ATOMIC_RELAXED, __HIP_MEMORY_SCOPE_AGENT);
                uint2 w;
                w.x = (uint)f2b(v0 * linv) | ((uint)f2b(v1 * linv) << 16);
                w.y = (uint)f2b(v2 * linv) | ((uint)f2b(v3 * linv) << 16);
                *(uint2*)(orow + db * 16) = w;
            }
        }
    }
}

extern "C" void kernel_launch(void* const* d_in, const int* in_sizes, int n_in,
                              void* d_out, int out_size, void* d_ws, size_t ws_size,
                              hipStream_t stream) {
    const float* x  = (const float*)d_in[0];
    const float* wq = (const float*)d_in[1];
    const float* wk = (const float*)d_in[2];
    const float* wv = (const float*)d_in[3];
    const float* wo = (const float*)d_in[4];
    const int* pos  = (const int*)d_in[5];

    const size_t NX = (size_t)4096 * 1024;
    const size_t NW = (size_t)1024 * 1024;

    ushort* q_ws  = (ushort*)d_ws;          // 8 MB each, 32 MiB total
    ushort* k_ws  = q_ws + NX;
    ushort* vt_ws = k_ws + NX;
    ushort* o_ws  = vt_ws + NX;
    // d_out (16 MB) doubles as bf16 scratch + rope table until the final GEMM
    ushort* xb  = (ushort*)d_out;           // 8 MB
    ushort* wqb = xb + NX;                  // 2 MB each
    ushort* wkb = wqb + NW;
    ushort* wvb = wkb + NW;
    float2* tab = (float2*)(wvb + NW);      // 512 KB

    // split-K scratch overlays xb/wqb (dead after gemm_qkv): 8 MB + 132 KB
    float* Opart = (float*)d_out;           // 512 tiles x 64x64 fp32
    float* lpart = Opart + (size_t)512 * 4096;
    uint*  cnt   = (uint*)(lpart + 512 * 64);

    cvt4_k<<<dim3(3840), 256, 0, stream>>>(x, wq, wk, wv, xb, wqb, wkb, wvb, pos, tab);
    gemm_qkv<<<dim3(768), 512, 0, stream>>>(xb, wqb, wkb, wvb, q_ws, k_ws, vt_ws, tab);
    hipMemsetAsync(d_out, 0, (size_t)(512 * 4096 + 512 * 64 + 512) * 4, stream);
    attn_k<<<dim3(1536), 256, 0, stream>>>(q_ws, k_ws, vt_ws, o_ws, Opart, lpart, cnt);
    cvt_k<<<dim3(512), 256, 0, stream>>>(wo, q_ws, (int)NW);   // q_ws dead now
    gemm_o<<<dim3(512), 256, 0, stream>>>(o_ws, q_ws, (float*)d_out);
}

// Round 10
// 192.029 us; speedup vs baseline: 2.0180x; 2.0180x over previous
//
#include <hip/hip_runtime.h>

typedef __attribute__((ext_vector_type(8))) short short8;
typedef __attribute__((ext_vector_type(4))) short short4v;
typedef __attribute__((ext_vector_type(4))) float floatx4;

__device__ inline ushort f2b(float f) {
    union { uint i; float f; } c; c.f = f;
    uint i = c.i;
    uint r = (i + 0x7FFFu + ((i >> 16) & 1u)) >> 16;
    return (ushort)r;
}

__device__ __forceinline__ void load_lds16(const ushort* g, ushort* l) {
    __builtin_amdgcn_global_load_lds((const __attribute__((address_space(1))) void*)g,
                                     (__attribute__((address_space(3))) void*)l, 16, 0, 0);
}

// Fused fp32->bf16 conversion of x, wq, wk, wv + RoPE cos/sin table (one launch).
__global__ __launch_bounds__(256) void cvt4_k(const float* __restrict__ x,
                                              const float* __restrict__ wq,
                                              const float* __restrict__ wk,
                                              const float* __restrict__ wv,
                                              ushort* __restrict__ xb,
                                              ushort* __restrict__ wqb,
                                              ushort* __restrict__ wkb,
                                              ushort* __restrict__ wvb,
                                              const int* __restrict__ pos,
                                              float2* __restrict__ tab) {
    const int blk = blockIdx.x;
    if (blk >= 3584) {
        const int idx = (blk - 3584) * 256 + threadIdx.x;   // 0..65535
        const int s = idx >> 5, fi = idx & 31;
        const float inv = exp2f(-(float)fi * 0.41524101186092557f);
        const float ang = (float)pos[s] * inv;
        float sn, cs;
        sincosf(ang, &sn, &cs);
        tab[idx] = make_float2(cs, sn);
        return;
    }
    const float* in; ushort* out; int base;
    if (blk < 2048)      { in = x;  out = xb;  base = blk; }
    else if (blk < 2560) { in = wq; out = wqb; base = blk - 2048; }
    else if (blk < 3072) { in = wk; out = wkb; base = blk - 2560; }
    else                 { in = wv; out = wvb; base = blk - 3072; }
    const int i = (base * 256 + threadIdx.x) * 8;
    float4 f0 = *(const float4*)(in + i);
    float4 f1 = *(const float4*)(in + i + 4);
    ushort u[8] = {f2b(f0.x), f2b(f0.y), f2b(f0.z), f2b(f0.w),
                   f2b(f1.x), f2b(f1.y), f2b(f1.z), f2b(f1.w)};
    *(uint4*)(out + i) = *(const uint4*)u;
}

// wo fp32->bf16 conversion (blocks [0,512)) + split-K combine (blocks [512,992)).
// Combine: O = (O0+O1)/(l0+l1), plain loads of L2-warm partials, bf16 store.
__global__ __launch_bounds__(256) void cvt_comb(const float* __restrict__ wo,
                                                ushort* __restrict__ wob,
                                                const float* __restrict__ Opart,
                                                const float* __restrict__ lpart,
                                                ushort* __restrict__ Og) {
    const int blk = blockIdx.x;
    const int tid = threadIdx.x;
    if (blk < 512) {
        const int i = (blk * 256 + tid) * 8;
        float4 f0 = *(const float4*)(wo + i);
        float4 f1 = *(const float4*)(wo + i + 4);
        ushort u[8] = {f2b(f0.x), f2b(f0.y), f2b(f0.z), f2b(f0.w),
                       f2b(f1.x), f2b(f1.y), f2b(f1.z), f2b(f1.w)};
        *(uint4*)(wob + i) = *(const uint4*)u;
        return;
    }
    const int tile = blk - 512;                 // 0..479
    const int qt = 31 - (tile >> 5);            // 31..17
    const int bh = tile & 31;
    const int b = bh >> 4, hh = bh & 15;
    const int bq = b * 2048;
    const int row = tid >> 2, cg = tid & 3;     // row 0..63, col-group 0..3
    const float* p0 = Opart + ((size_t)tile * 2) * 4096 + row * 64 + cg * 16;
    const float* p1 = p0 + 4096;
    const float l = lpart[tile * 128 + row] + lpart[tile * 128 + 64 + row];
    const float linv = 1.0f / l;
    ushort u[16];
#pragma unroll
    for (int j = 0; j < 4; ++j) {
        float4 a = *(const float4*)(p0 + j * 4);
        float4 c = *(const float4*)(p1 + j * 4);
        u[j * 4 + 0] = f2b((a.x + c.x) * linv);
        u[j * 4 + 1] = f2b((a.y + c.y) * linv);
        u[j * 4 + 2] = f2b((a.z + c.z) * linv);
        u[j * 4 + 3] = f2b((a.w + c.w) * linv);
    }
    ushort* orow = Og + (size_t)(bq + qt * 64 + row) * 1024 + hh * 64 + cg * 16;
    *(uint4*)(orow)     = ((const uint4*)u)[0];
    *(uint4*)(orow + 8) = ((const uint4*)u)[1];
}

// 128x128 GEMM body, K=1024, BK=32, EIGHT waves (2m x 4n of 64x32 each).
// Verified 2-phase skeleton: double-buffered LDS, one __syncthreads per K-iter.
template <bool OUTF32>
__device__ __forceinline__ void gemm_body8(ushort* As, ushort* Bs,   // [2][4096] each
                                           const ushort* __restrict__ A,
                                           const ushort* __restrict__ B,
                                           void* __restrict__ C,
                                           int N, int m0, int n0,
                                           bool doRope, const float2* __restrict__ tab,
                                           float oscale) {
    const int tid = threadIdx.x;            // 0..511
    const int wave = tid >> 6, lane = tid & 63;
    const int quad = lane >> 4, l16 = lane & 15;
    const int wm = (wave >> 2) * 64, wn = (wave & 3) * 32;

    floatx4 acc[4][2] = {};

    const int rA = tid >> 2, jgA = ((tid & 3) - (rA >> 1)) & 3;
    const ushort* ga = A + (size_t)(m0 + rA) * 1024 + jgA * 8;
    const ushort* gb = B + (size_t)(n0 + rA) * 1024 + jgA * 8;

    load_lds16(ga, As + tid * 8);
    load_lds16(gb, Bs + tid * 8);
    __syncthreads();

    for (int kt = 0; kt < 32; ++kt) {
        const int cur = kt & 1;
        if (kt + 1 < 32) {
            const int nb = (cur ^ 1) * 4096;
            load_lds16(ga + (kt + 1) * 32, As + nb + tid * 8);
            load_lds16(gb + (kt + 1) * 32, Bs + nb + tid * 8);
        }
        const ushort* as = As + cur * 4096;
        const ushort* bs = Bs + cur * 4096;
        short8 af[4], bf[2];
#pragma unroll
        for (int i = 0; i < 4; ++i) {
            const int ra = wm + i * 16 + l16;
            af[i] = *(const short8*)(as + ra * 32 + (((quad + (ra >> 1)) & 3) << 3));
        }
#pragma unroll
        for (int j = 0; j < 2; ++j) {
            const int rb = wn + j * 16 + l16;
            bf[j] = *(const short8*)(bs + rb * 32 + (((quad + (rb >> 1)) & 3) << 3));
        }
#pragma unroll
        for (int mi = 0; mi < 4; ++mi)
#pragma unroll
            for (int ni = 0; ni < 2; ++ni)
                acc[mi][ni] = __builtin_amdgcn_mfma_f32_16x16x32_bf16(af[mi], bf[ni], acc[mi][ni], 0, 0, 0);
        __syncthreads();
    }
#pragma unroll
    for (int mi = 0; mi < 4; ++mi) {
        const int row = m0 + wm + mi * 16 + quad * 4;
#pragma unroll
        for (int ni = 0; ni < 2; ++ni) {
            const int col = n0 + wn + ni * 16 + l16;
            const int fi = ((wn + ni * 16 + l16) & 63) >> 1;
#pragma unroll
            for (int r = 0; r < 4; ++r) {
                float v = acc[mi][ni][r];
                if (doRope) {
                    const float other = __shfl_xor(v, 1);
                    const float2 cs = tab[((row + r) & 2047) * 32 + fi];
                    v = (col & 1) ? (other * cs.y + v * cs.x) : (v * cs.x - other * cs.y);
                }
                v *= oscale;
                if (OUTF32) ((float*)C)[(size_t)(row + r) * N + col] = v;
                else        ((ushort*)C)[(size_t)(row + r) * N + col] = f2b(v);
            }
        }
    }
}

// Fused Q/K/Vt GEMM: 768 blocks x 512 threads (8 waves). R7-verified.
__global__ __launch_bounds__(512) void gemm_qkv(const ushort* __restrict__ xb,
                                                const ushort* __restrict__ wqb,
                                                const ushort* __restrict__ wkb,
                                                const ushort* __restrict__ wvb,
                                                ushort* __restrict__ q,
                                                ushort* __restrict__ k,
                                                ushort* __restrict__ vt,
                                                const float2* __restrict__ tab) {
    __shared__ __align__(16) ushort As[8192], Bs[8192];
    const int blk = blockIdx.x;
    const int job = blk >> 8, r = blk & 255;
    const ushort *A, *B;
    ushort* C;
    int N, m0, n0;
    bool rope;
    float osc;
    if (job == 0)      { A = xb;  B = wqb; C = q;  N = 1024; m0 = (r >> 3) * 128; n0 = (r & 7) * 128; rope = true;  osc = 0.18033688011112042f; }
    else if (job == 1) { A = xb;  B = wkb; C = k;  N = 1024; m0 = (r >> 3) * 128; n0 = (r & 7) * 128; rope = true;  osc = 1.0f; }
    else               { A = wvb; B = xb;  C = vt; N = 4096; m0 = (r & 7) * 128;  n0 = (r >> 3) * 128; rope = false; osc = 1.0f; }
    gemm_body8<false>(As, Bs, A, B, C, N, m0, n0, rope, tab, osc);
}

// Output projection: C fp32 = O[4096][1024] * wo[1024][1024]^T.
// R4-verified form: 128x64 tiles, 512 blocks = 2 blocks/CU, bf16 B via cvt_comb.
__global__ __launch_bounds__(256) void gemm_o(const ushort* __restrict__ A,
                                              const ushort* __restrict__ B,
                                              float* __restrict__ C) {
    __shared__ __align__(16) ushort As[8192];   // 2 bufs x 128 rows x 32 cols
    __shared__ __align__(16) ushort Bs[4096];   // 2 bufs x  64 rows x 32 cols

    const int blk = blockIdx.x;
    const int m0 = (blk >> 4) * 128, n0 = (blk & 15) * 64;

    const int tid = threadIdx.x;
    const int wave = tid >> 6, lane = tid & 63;
    const int quad = lane >> 4, l16 = lane & 15;
    const int wm = (wave >> 1) * 64, wn = (wave & 1) * 32;

    floatx4 acc[4][2] = {};

    const int cA1 = tid, cA2 = tid + 256, cBc = tid;
    const int rA1 = cA1 >> 2, jg1 = ((cA1 & 3) - (rA1 >> 1)) & 3;
    const int rA2 = cA2 >> 2, jg2 = ((cA2 & 3) - (rA2 >> 1)) & 3;
    const int rBc = cBc >> 2, jgB = ((cBc & 3) - (rBc >> 1)) & 3;
    const ushort* ga1 = A + (size_t)(m0 + rA1) * 1024 + jg1 * 8;
    const ushort* ga2 = A + (size_t)(m0 + rA2) * 1024 + jg2 * 8;
    const ushort* gb1 = B + (size_t)(n0 + rBc) * 1024 + jgB * 8;

    load_lds16(ga1, As + cA1 * 8);
    load_lds16(ga2, As + cA2 * 8);
    load_lds16(gb1, Bs + cBc * 8);
    __syncthreads();

    for (int kt = 0; kt < 32; ++kt) {
        const int cur = kt & 1;
        if (kt + 1 < 32) {
            const int nbA = (cur ^ 1) * 4096;
            const int nbB = (cur ^ 1) * 2048;
            load_lds16(ga1 + (kt + 1) * 32, As + nbA + cA1 * 8);
            load_lds16(ga2 + (kt + 1) * 32, As + nbA + cA2 * 8);
            load_lds16(gb1 + (kt + 1) * 32, Bs + nbB + cBc * 8);
        }
        const ushort* as = As + cur * 4096;
        const ushort* bs = Bs + cur * 2048;
        short8 af[4], bf[2];
#pragma unroll
        for (int i = 0; i < 4; ++i) {
            const int ra = wm + i * 16 + l16;
            af[i] = *(const short8*)(as + ra * 32 + (((quad + (ra >> 1)) & 3) << 3));
        }
#pragma unroll
        for (int j = 0; j < 2; ++j) {
            const int rb = wn + j * 16 + l16;
            bf[j] = *(const short8*)(bs + rb * 32 + (((quad + (rb >> 1)) & 3) << 3));
        }
#pragma unroll
        for (int mi = 0; mi < 4; ++mi)
#pragma unroll
            for (int ni = 0; ni < 2; ++ni)
                acc[mi][ni] = __builtin_amdgcn_mfma_f32_16x16x32_bf16(af[mi], bf[ni], acc[mi][ni], 0, 0, 0);
        __syncthreads();
    }
#pragma unroll
    for (int mi = 0; mi < 4; ++mi) {
        const int row = m0 + wm + mi * 16 + quad * 4;
#pragma unroll
        for (int ni = 0; ni < 2; ++ni) {
            const int col = n0 + wn + ni * 16 + l16;
#pragma unroll
            for (int r = 0; r < 4; ++r)
                C[(size_t)(row + r) * 1024 + col] = acc[mi][ni][r];
        }
    }
}

// Causal flash attention, SPLIT-K with ATOMIC-FREE combine (R9 lesson: the
// atomicAdd storm cost 200 us; plain stores + stream-ordered merge instead).
// Tiles qt>=17 split into two k-halves (9..16 steps), each half plain-stores
// fp32 (O,l) partials into its PRIVATE slot; cvt_comb merges. Tiles qt<=16
// run whole (1..17 steps) and write Og directly. Max steps/block: 32 -> 17.
// Grid 1504, heavy-first.
__global__ __launch_bounds__(256, 4) void attn_k(const ushort* __restrict__ Qg,
                                                 const ushort* __restrict__ Kg,
                                                 const ushort* __restrict__ Vtg,
                                                 ushort* __restrict__ Og,
                                                 float* __restrict__ Opart,
                                                 float* __restrict__ lpart) {
    __shared__ __align__(16) ushort Ks[2][4096];   // [s][d] chunk-swizzled
    __shared__ __align__(16) ushort Vs[2][4096];   // [d][s] chunk-swizzled

    const int tid = threadIdx.x;
    const int wave = tid >> 6, lane = tid & 63;
    const int quad = lane >> 4, l16 = lane & 15;
    const int blk = blockIdx.x;

    int bh, qt, k0, ks, tile, half;
    bool split, hasDiag;
    if (blk < 960) {                        // split halves of qt in [17,31]
        tile = blk >> 1;                    // 0..479
        half = blk & 1;
        qt = 31 - (tile >> 5);              // 31..17, heavy-first
        bh = tile & 31;
        const int nk = qt + 1, hf = nk >> 1;
        k0 = half ? hf : 0;
        ks = half ? (nk - hf) : hf;         // 9..16 steps
        hasDiag = (half == 1);
        split = true;
    } else {                                // whole tiles qt in [0,16], heavy-first
        const int idx = blk - 960;
        bh = idx & 31;
        qt = 16 - (idx >> 5);
        k0 = 0; ks = qt + 1;                // 1..17 steps
        hasDiag = true; split = false; tile = 0; half = 0;
    }
    const int b = bh >> 4, hh = bh & 15;
    const int bq = b * 2048;
    const int wl = wave * 16 + l16;        // q-row within 64-row tile

    const int cA = tid, cB = tid + 256;
    const int sA = cA >> 3, jA = ((cA & 7) - sA) & 7;
    const int sB = cB >> 3, jB = ((cB & 7) - sB) & 7;
    const ushort* kgA = Kg + (size_t)(bq + k0 * 64 + sA) * 1024 + hh * 64 + jA * 8;
    const ushort* kgB = Kg + (size_t)(bq + k0 * 64 + sB) * 1024 + hh * 64 + jB * 8;
    const ushort* vgA = Vtg + (size_t)(hh * 64 + sA) * 4096 + bq + k0 * 64 + jA * 8;
    const ushort* vgB = Vtg + (size_t)(hh * 64 + sB) * 4096 + bq + k0 * 64 + jB * 8;

    // kt-invariant LDS read offsets (ushort units)
    const int kb0 = l16 * 64 + (((quad + l16) & 7) << 3);
    const int kb1 = l16 * 64 + (((quad + 4 + l16) & 7) << 3);
    int vbs[4];
#pragma unroll
    for (int cb = 0; cb < 4; ++cb)
        vbs[cb] = l16 * 64 + (((cb * 2 + (quad >> 1) + l16) & 7) << 3) + (quad & 1) * 4;

    const ushort* qrow = Qg + (size_t)(bq + qt * 64 + wl) * 1024 + hh * 64 + quad * 8;
    const short8 qf0 = *(const short8*)qrow;
    const short8 qf1 = *(const short8*)(qrow + 32);

    floatx4 od[4] = {};
    float l_st = 0.0f;                      // per-lane partial; shfl-reduced at end

    load_lds16(kgA, &Ks[0][cA * 8]);
    load_lds16(kgB, &Ks[0][cB * 8]);
    load_lds16(vgA, &Vs[0][cA * 8]);
    load_lds16(vgB, &Vs[0][cB * 8]);
    __syncthreads();

    const ushort* kgA2 = kgA + 65536;
    const ushort* kgB2 = kgB + 65536;
    const ushort* vgA2 = vgA + 64;
    const ushort* vgB2 = vgB + 64;

    auto step = [&](int kt, bool diag, bool pref) {
        const int cur = kt & 1;
        if (pref) {
            const int nxt = cur ^ 1;
            load_lds16(kgA2, &Ks[nxt][cA * 8]);
            load_lds16(kgB2, &Ks[nxt][cB * 8]);
            load_lds16(vgA2, &Vs[nxt][cA * 8]);
            load_lds16(vgB2, &Vs[nxt][cB * 8]);
            kgA2 += 65536; kgB2 += 65536; vgA2 += 64; vgB2 += 64;
        }
        const ushort* kc = &Ks[cur][0];
        const ushort* vc = &Vs[cur][0];

        // S^T = K Q^T  (Q pre-scaled, st already in log2 domain)
        floatx4 st[4];
        __builtin_amdgcn_s_setprio(1);
#pragma unroll
        for (int cb = 0; cb < 4; ++cb) {
            short8 kf0 = *(const short8*)(kc + kb0 + cb * 1024);
            short8 kf1 = *(const short8*)(kc + kb1 + cb * 1024);
            floatx4 z = {};
            z = __builtin_amdgcn_mfma_f32_16x16x32_bf16(kf0, qf0, z, 0, 0, 0);
            z = __builtin_amdgcn_mfma_f32_16x16x32_bf16(kf1, qf1, z, 0, 0, 0);
            st[cb] = z;
        }
        __builtin_amdgcn_s_setprio(0);

        float pv[4][4];
        float sum = 0.0f;
#pragma unroll
        for (int cb = 0; cb < 4; ++cb) {
            const int scb = cb * 16 + quad * 4;
#pragma unroll
            for (int r = 0; r < 4; ++r) {
                float e = exp2f(st[cb][r]);
                if (diag && (scb + r > wl)) e = 0.0f;
                pv[cb][r] = e;
                sum += e;
            }
        }
        l_st += sum;

        short4v pb[4];
#pragma unroll
        for (int cb = 0; cb < 4; ++cb) {
            uint lo_, hi_;
            asm("v_cvt_pk_bf16_f32 %0, %1, %2" : "=v"(lo_) : "v"(pv[cb][0]), "v"(pv[cb][1]));
            asm("v_cvt_pk_bf16_f32 %0, %1, %2" : "=v"(hi_) : "v"(pv[cb][2]), "v"(pv[cb][3]));
            union { uint u[2]; short4v s; } cvu;
            cvu.u[0] = lo_; cvu.u[1] = hi_;
            pb[cb] = cvu.s;
        }

        __builtin_amdgcn_s_setprio(1);
#pragma unroll
        for (int db = 0; db < 4; ++db) {
#pragma unroll
            for (int cb = 0; cb < 4; ++cb) {
                short4v vf = *(const short4v*)(vc + vbs[cb] + db * 1024);
                od[db] = __builtin_amdgcn_mfma_f32_16x16x16bf16_1k(vf, pb[cb], od[db], 0, 0, 0);
            }
        }
        __builtin_amdgcn_s_setprio(0);
        if (pref) __syncthreads();   // protect buffer reuse; last iter skips
    };

    for (int s = 0; s < ks - 1; ++s) step(s, false, true);
    step(ks - 1, hasDiag, false);           // diag mask only on the owning half

    // cross-quad row reduction (once, off the per-step critical path)
    l_st += __shfl_xor(l_st, 16);
    l_st += __shfl_xor(l_st, 32);

    if (!split) {
        const float linv = 1.0f / l_st;
        ushort* orow = Og + (size_t)(bq + qt * 64 + wl) * 1024 + hh * 64 + quad * 4;
#pragma unroll
        for (int db = 0; db < 4; ++db) {
            uint2 w;
            w.x = (uint)f2b(od[db][0] * linv) | ((uint)f2b(od[db][1] * linv) << 16);
            w.y = (uint)f2b(od[db][2] * linv) | ((uint)f2b(od[db][3] * linv) << 16);
            *(uint2*)(orow + db * 16) = w;
        }
    } else {
        // private-slot fp32 partials, plain vector stores (no atomics)
        float* op = Opart + ((size_t)(tile * 2 + half)) * 4096 + wl * 64 + quad * 4;
#pragma unroll
        for (int db = 0; db < 4; ++db)
            *(floatx4*)(op + db * 16) = od[db];
        if (quad == 0) lpart[(tile * 2 + half) * 64 + wl] = l_st;
    }
}

extern "C" void kernel_launch(void* const* d_in, const int* in_sizes, int n_in,
                              void* d_out, int out_size, void* d_ws, size_t ws_size,
                              hipStream_t stream) {
    const float* x  = (const float*)d_in[0];
    const float* wq = (const float*)d_in[1];
    const float* wk = (const float*)d_in[2];
    const float* wv = (const float*)d_in[3];
    const float* wo = (const float*)d_in[4];
    const int* pos  = (const int*)d_in[5];

    const size_t NX = (size_t)4096 * 1024;
    const size_t NW = (size_t)1024 * 1024;

    ushort* q_ws  = (ushort*)d_ws;          // 8 MB each, 32 MiB total
    ushort* k_ws  = q_ws + NX;
    ushort* vt_ws = k_ws + NX;
    ushort* o_ws  = vt_ws + NX;
    // d_out (16 MB) doubles as bf16 scratch + rope table until the final GEMM
    ushort* xb  = (ushort*)d_out;           // 8 MB
    ushort* wqb = xb + NX;                  // 2 MB each
    ushort* wkb = wqb + NW;
    ushort* wvb = wkb + NW;
    float2* tab = (float2*)(wvb + NW);      // 512 KB

    // split-K scratch overlays d_out (all dead after gemm_qkv):
    // Opart 480 tiles x 2 halves x 64x64 fp32 = 15.0 MB; lpart 240 KB.
    float* Opart = (float*)d_out;
    float* lpart = Opart + (size_t)480 * 2 * 4096;

    cvt4_k<<<dim3(3840), 256, 0, stream>>>(x, wq, wk, wv, xb, wqb, wkb, wvb, pos, tab);
    gemm_qkv<<<dim3(768), 512, 0, stream>>>(xb, wqb, wkb, wvb, q_ws, k_ws, vt_ws, tab);
    attn_k<<<dim3(1504), 256, 0, stream>>>(q_ws, k_ws, vt_ws, o_ws, Opart, lpart);
    cvt_comb<<<dim3(992), 256, 0, stream>>>(wo, q_ws, Opart, lpart, o_ws);
    gemm_o<<<dim3(512), 256, 0, stream>>>(o_ws, q_ws, (float*)d_out);
}

// Round 11
// 185.013 us; speedup vs baseline: 2.0946x; 1.0379x over previous
//
#include <hip/hip_runtime.h>

typedef __attribute__((ext_vector_type(8))) short short8;
typedef __attribute__((ext_vector_type(4))) short short4v;
typedef __attribute__((ext_vector_type(4))) float floatx4;

__device__ inline ushort f2b(float f) {
    union { uint i; float f; } c; c.f = f;
    uint i = c.i;
    uint r = (i + 0x7FFFu + ((i >> 16) & 1u)) >> 16;
    return (ushort)r;
}

__device__ __forceinline__ void load_lds16(const ushort* g, ushort* l) {
    __builtin_amdgcn_global_load_lds((const __attribute__((address_space(1))) void*)g,
                                     (__attribute__((address_space(3))) void*)l, 16, 0, 0);
}

// Fused fp32->bf16 conversion of x, wq, wk, wv + RoPE cos/sin table (one launch).
__global__ __launch_bounds__(256) void cvt4_k(const float* __restrict__ x,
                                              const float* __restrict__ wq,
                                              const float* __restrict__ wk,
                                              const float* __restrict__ wv,
                                              ushort* __restrict__ xb,
                                              ushort* __restrict__ wqb,
                                              ushort* __restrict__ wkb,
                                              ushort* __restrict__ wvb,
                                              const int* __restrict__ pos,
                                              float2* __restrict__ tab) {
    const int blk = blockIdx.x;
    if (blk >= 3584) {
        const int idx = (blk - 3584) * 256 + threadIdx.x;   // 0..65535
        const int s = idx >> 5, fi = idx & 31;
        const float inv = exp2f(-(float)fi * 0.41524101186092557f);
        const float ang = (float)pos[s] * inv;
        float sn, cs;
        sincosf(ang, &sn, &cs);
        tab[idx] = make_float2(cs, sn);
        return;
    }
    const float* in; ushort* out; int base;
    if (blk < 2048)      { in = x;  out = xb;  base = blk; }
    else if (blk < 2560) { in = wq; out = wqb; base = blk - 2048; }
    else if (blk < 3072) { in = wk; out = wkb; base = blk - 2560; }
    else                 { in = wv; out = wvb; base = blk - 3072; }
    const int i = (base * 256 + threadIdx.x) * 8;
    float4 f0 = *(const float4*)(in + i);
    float4 f1 = *(const float4*)(in + i + 4);
    ushort u[8] = {f2b(f0.x), f2b(f0.y), f2b(f0.z), f2b(f0.w),
                   f2b(f1.x), f2b(f1.y), f2b(f1.z), f2b(f1.w)};
    *(uint4*)(out + i) = *(const uint4*)u;
}

__global__ __launch_bounds__(256) void cvt_k(const float* __restrict__ in,
                                             ushort* __restrict__ out, int n) {
    const int i = (blockIdx.x * 256 + threadIdx.x) * 8;
    if (i >= n) return;
    float4 f0 = *(const float4*)(in + i);
    float4 f1 = *(const float4*)(in + i + 4);
    ushort u[8] = {f2b(f0.x), f2b(f0.y), f2b(f0.z), f2b(f0.w),
                   f2b(f1.x), f2b(f1.y), f2b(f1.z), f2b(f1.w)};
    *(uint4*)(out + i) = *(const uint4*)u;
}

// 128x128 GEMM body, K=1024, BK=32, EIGHT waves (2m x 4n of 64x32 each).
// Verified 2-phase skeleton: double-buffered LDS, one __syncthreads per K-iter.
template <bool OUTF32>
__device__ __forceinline__ void gemm_body8(ushort* As, ushort* Bs,   // [2][4096] each
                                           const ushort* __restrict__ A,
                                           const ushort* __restrict__ B,
                                           void* __restrict__ C,
                                           int N, int m0, int n0,
                                           bool doRope, const float2* __restrict__ tab,
                                           float oscale) {
    const int tid = threadIdx.x;            // 0..511
    const int wave = tid >> 6, lane = tid & 63;
    const int quad = lane >> 4, l16 = lane & 15;
    const int wm = (wave >> 2) * 64, wn = (wave & 3) * 32;

    floatx4 acc[4][2] = {};

    const int rA = tid >> 2, jgA = ((tid & 3) - (rA >> 1)) & 3;
    const ushort* ga = A + (size_t)(m0 + rA) * 1024 + jgA * 8;
    const ushort* gb = B + (size_t)(n0 + rA) * 1024 + jgA * 8;

    load_lds16(ga, As + tid * 8);
    load_lds16(gb, Bs + tid * 8);
    __syncthreads();

    for (int kt = 0; kt < 32; ++kt) {
        const int cur = kt & 1;
        if (kt + 1 < 32) {
            const int nb = (cur ^ 1) * 4096;
            load_lds16(ga + (kt + 1) * 32, As + nb + tid * 8);
            load_lds16(gb + (kt + 1) * 32, Bs + nb + tid * 8);
        }
        const ushort* as = As + cur * 4096;
        const ushort* bs = Bs + cur * 4096;
        short8 af[4], bf[2];
#pragma unroll
        for (int i = 0; i < 4; ++i) {
            const int ra = wm + i * 16 + l16;
            af[i] = *(const short8*)(as + ra * 32 + (((quad + (ra >> 1)) & 3) << 3));
        }
#pragma unroll
        for (int j = 0; j < 2; ++j) {
            const int rb = wn + j * 16 + l16;
            bf[j] = *(const short8*)(bs + rb * 32 + (((quad + (rb >> 1)) & 3) << 3));
        }
#pragma unroll
        for (int mi = 0; mi < 4; ++mi)
#pragma unroll
            for (int ni = 0; ni < 2; ++ni)
                acc[mi][ni] = __builtin_amdgcn_mfma_f32_16x16x32_bf16(af[mi], bf[ni], acc[mi][ni], 0, 0, 0);
        __syncthreads();
    }
#pragma unroll
    for (int mi = 0; mi < 4; ++mi) {
        const int row = m0 + wm + mi * 16 + quad * 4;
#pragma unroll
        for (int ni = 0; ni < 2; ++ni) {
            const int col = n0 + wn + ni * 16 + l16;
            const int fi = ((wn + ni * 16 + l16) & 63) >> 1;
#pragma unroll
            for (int r = 0; r < 4; ++r) {
                float v = acc[mi][ni][r];
                if (doRope) {
                    const float other = __shfl_xor(v, 1);
                    const float2 cs = tab[((row + r) & 2047) * 32 + fi];
                    v = (col & 1) ? (other * cs.y + v * cs.x) : (v * cs.x - other * cs.y);
                }
                v *= oscale;
                if (OUTF32) ((float*)C)[(size_t)(row + r) * N + col] = v;
                else        ((ushort*)C)[(size_t)(row + r) * N + col] = f2b(v);
            }
        }
    }
}

// Fused Q/K/Vt GEMM: 768 blocks x 512 threads (8 waves). R7-verified.
__global__ __launch_bounds__(512) void gemm_qkv(const ushort* __restrict__ xb,
                                                const ushort* __restrict__ wqb,
                                                const ushort* __restrict__ wkb,
                                                const ushort* __restrict__ wvb,
                                                ushort* __restrict__ q,
                                                ushort* __restrict__ k,
                                                ushort* __restrict__ vt,
                                                const float2* __restrict__ tab) {
    __shared__ __align__(16) ushort As[8192], Bs[8192];
    const int blk = blockIdx.x;
    const int job = blk >> 8, r = blk & 255;
    const ushort *A, *B;
    ushort* C;
    int N, m0, n0;
    bool rope;
    float osc;
    if (job == 0)      { A = xb;  B = wqb; C = q;  N = 1024; m0 = (r >> 3) * 128; n0 = (r & 7) * 128; rope = true;  osc = 0.18033688011112042f; }
    else if (job == 1) { A = xb;  B = wkb; C = k;  N = 1024; m0 = (r >> 3) * 128; n0 = (r & 7) * 128; rope = true;  osc = 1.0f; }
    else               { A = wvb; B = xb;  C = vt; N = 4096; m0 = (r & 7) * 128;  n0 = (r >> 3) * 128; rope = false; osc = 1.0f; }
    gemm_body8<false>(As, Bs, A, B, C, N, m0, n0, rope, tab, osc);
}

// Output projection: C fp32 = O[4096][1024] * wo[1024][1024]^T.
// R7-transformation applied: 128x64 tile, EIGHT waves (2m x 4n of 64x16),
// 512-thread blocks, 512 blocks = 2 blocks/CU -> 16 waves/CU (was 8).
// Same 2-phase skeleton + swizzle; B staged by waves 0-3 (256 chunks).
__global__ __launch_bounds__(512) void gemm_o(const ushort* __restrict__ A,
                                              const ushort* __restrict__ B,
                                              float* __restrict__ C) {
    __shared__ __align__(16) ushort As[8192];   // 2 bufs x 128 rows x 32 cols
    __shared__ __align__(16) ushort Bs[4096];   // 2 bufs x  64 rows x 32 cols

    const int blk = blockIdx.x;
    const int m0 = (blk >> 4) * 128, n0 = (blk & 15) * 64;

    const int tid = threadIdx.x;            // 0..511
    const int wave = tid >> 6, lane = tid & 63;
    const int quad = lane >> 4, l16 = lane & 15;
    const int wm = (wave >> 2) * 64, wn = (wave & 3) * 16;

    floatx4 acc[4] = {};

    const int rA = tid >> 2, jgA = ((tid & 3) - (rA >> 1)) & 3;
    const ushort* ga = A + (size_t)(m0 + rA) * 1024 + jgA * 8;
    const int rB = (tid & 255) >> 2, jgB = (((tid & 255) & 3) - (rB >> 1)) & 3;
    const ushort* gb = B + (size_t)(n0 + rB) * 1024 + jgB * 8;

    load_lds16(ga, As + tid * 8);
    if (tid < 256) load_lds16(gb, Bs + tid * 8);
    __syncthreads();

    for (int kt = 0; kt < 32; ++kt) {
        const int cur = kt & 1;
        if (kt + 1 < 32) {
            load_lds16(ga + (kt + 1) * 32, As + (cur ^ 1) * 4096 + tid * 8);
            if (tid < 256)
                load_lds16(gb + (kt + 1) * 32, Bs + (cur ^ 1) * 2048 + tid * 8);
        }
        const ushort* as = As + cur * 4096;
        const ushort* bs = Bs + cur * 2048;
        short8 af[4], bf;
#pragma unroll
        for (int i = 0; i < 4; ++i) {
            const int ra = wm + i * 16 + l16;
            af[i] = *(const short8*)(as + ra * 32 + (((quad + (ra >> 1)) & 3) << 3));
        }
        {
            const int rb = wn + l16;
            bf = *(const short8*)(bs + rb * 32 + (((quad + (rb >> 1)) & 3) << 3));
        }
#pragma unroll
        for (int mi = 0; mi < 4; ++mi)
            acc[mi] = __builtin_amdgcn_mfma_f32_16x16x32_bf16(af[mi], bf, acc[mi], 0, 0, 0);
        __syncthreads();
    }
#pragma unroll
    for (int mi = 0; mi < 4; ++mi) {
        const int row = m0 + wm + mi * 16 + quad * 4;
        const int col = n0 + wn + l16;
#pragma unroll
        for (int r = 0; r < 4; ++r)
            C[(size_t)(row + r) * 1024 + col] = acc[mi][r];
    }
}

// Causal flash attention (R8-verified structure, simplest known-best form).
// 1024 blocks, all co-resident (4/CU); balanced qt map; diag tile peeled.
// R10-verified micro-opt kept: per-lane l partial, cross-quad shfl deferred
// out of the step loop (2 shfls removed from every step's critical path).
__global__ __launch_bounds__(256, 4) void attn_k(const ushort* __restrict__ Qg,
                                                 const ushort* __restrict__ Kg,
                                                 const ushort* __restrict__ Vtg,
                                                 ushort* __restrict__ Og) {
    __shared__ __align__(16) ushort Ks[2][4096];   // [s][d] chunk-swizzled
    __shared__ __align__(16) ushort Vs[2][4096];   // [d][s] chunk-swizzled

    const int tid = threadIdx.x;
    const int wave = tid >> 6, lane = tid & 63;
    const int quad = lane >> 4, l16 = lane & 15;
    const int blk = blockIdx.x;
    const int g = blk >> 8, rem = blk & 255;
    const int t = rem >> 5, bh = rem & 31;
    int qt;
    if (g == 0)      qt = 31 - t;
    else if (g == 1) qt = 23 - t;
    else if (g == 2) qt = t;
    else             qt = 8 + t;
    const int b = bh >> 4, h = bh & 15;
    const int bq = b * 2048;
    const int wl = wave * 16 + l16;                // q-row within 64-row tile
    const int nk = qt + 1, dt = nk - 1;

    const int cA = tid, cB = tid + 256;
    const int sA = cA >> 3, jA = ((cA & 7) - sA) & 7;
    const int sB = cB >> 3, jB = ((cB & 7) - sB) & 7;
    const ushort* kgA = Kg + (size_t)(bq + sA) * 1024 + h * 64 + jA * 8;
    const ushort* kgB = Kg + (size_t)(bq + sB) * 1024 + h * 64 + jB * 8;
    const ushort* vgA = Vtg + (size_t)(h * 64 + sA) * 4096 + bq + jA * 8;
    const ushort* vgB = Vtg + (size_t)(h * 64 + sB) * 4096 + bq + jB * 8;

    // kt-invariant LDS read offsets (ushort units)
    const int kb0 = l16 * 64 + (((quad + l16) & 7) << 3);
    const int kb1 = l16 * 64 + (((quad + 4 + l16) & 7) << 3);
    int vbs[4];
#pragma unroll
    for (int cb = 0; cb < 4; ++cb)
        vbs[cb] = l16 * 64 + (((cb * 2 + (quad >> 1) + l16) & 7) << 3) + (quad & 1) * 4;

    const ushort* qrow = Qg + (size_t)(bq + qt * 64 + wl) * 1024 + h * 64 + quad * 8;
    const short8 qf0 = *(const short8*)qrow;
    const short8 qf1 = *(const short8*)(qrow + 32);

    floatx4 od[4] = {};
    float l_st = 0.0f;                      // per-lane partial; shfl-reduced at end

    load_lds16(kgA, &Ks[0][cA * 8]);
    load_lds16(kgB, &Ks[0][cB * 8]);
    load_lds16(vgA, &Vs[0][cA * 8]);
    load_lds16(vgB, &Vs[0][cB * 8]);
    __syncthreads();

    const ushort* kgA2 = kgA + 65536;
    const ushort* kgB2 = kgB + 65536;
    const ushort* vgA2 = vgA + 64;
    const ushort* vgB2 = vgB + 64;

    auto step = [&](int kt, bool diag, bool pref) {
        const int cur = kt & 1;
        if (pref) {
            const int nxt = cur ^ 1;
            load_lds16(kgA2, &Ks[nxt][cA * 8]);
            load_lds16(kgB2, &Ks[nxt][cB * 8]);
            load_lds16(vgA2, &Vs[nxt][cA * 8]);
            load_lds16(vgB2, &Vs[nxt][cB * 8]);
            kgA2 += 65536; kgB2 += 65536; vgA2 += 64; vgB2 += 64;
        }
        const ushort* kc = &Ks[cur][0];
        const ushort* vc = &Vs[cur][0];

        // S^T = K Q^T  (Q pre-scaled, st already in log2 domain)
        floatx4 st[4];
        __builtin_amdgcn_s_setprio(1);
#pragma unroll
        for (int cb = 0; cb < 4; ++cb) {
            short8 kf0 = *(const short8*)(kc + kb0 + cb * 1024);
            short8 kf1 = *(const short8*)(kc + kb1 + cb * 1024);
            floatx4 z = {};
            z = __builtin_amdgcn_mfma_f32_16x16x32_bf16(kf0, qf0, z, 0, 0, 0);
            z = __builtin_amdgcn_mfma_f32_16x16x32_bf16(kf1, qf1, z, 0, 0, 0);
            st[cb] = z;
        }
        __builtin_amdgcn_s_setprio(0);

        float pv[4][4];
        float sum = 0.0f;
#pragma unroll
        for (int cb = 0; cb < 4; ++cb) {
            const int scb = cb * 16 + quad * 4;
#pragma unroll
            for (int r = 0; r < 4; ++r) {
                float e = exp2f(st[cb][r]);
                if (diag && (scb + r > wl)) e = 0.0f;
                pv[cb][r] = e;
                sum += e;
            }
        }
        l_st += sum;                        // lane partial; cross-quad shfl deferred

        short4v pb[4];
#pragma unroll
        for (int cb = 0; cb < 4; ++cb) {
            uint lo_, hi_;
            asm("v_cvt_pk_bf16_f32 %0, %1, %2" : "=v"(lo_) : "v"(pv[cb][0]), "v"(pv[cb][1]));
            asm("v_cvt_pk_bf16_f32 %0, %1, %2" : "=v"(hi_) : "v"(pv[cb][2]), "v"(pv[cb][3]));
            union { uint u[2]; short4v s; } cvu;
            cvu.u[0] = lo_; cvu.u[1] = hi_;
            pb[cb] = cvu.s;
        }

        __builtin_amdgcn_s_setprio(1);
#pragma unroll
        for (int db = 0; db < 4; ++db) {
#pragma unroll
            for (int cb = 0; cb < 4; ++cb) {
                short4v vf = *(const short4v*)(vc + vbs[cb] + db * 1024);
                od[db] = __builtin_amdgcn_mfma_f32_16x16x16bf16_1k(vf, pb[cb], od[db], 0, 0, 0);
            }
        }
        __builtin_amdgcn_s_setprio(0);
        if (pref) __syncthreads();   // protect buffer reuse; last iter skips
    };

    for (int kt = 0; kt < dt; ++kt) step(kt, false, true);   // maskless main loop
    step(dt, true, false);                                    // peeled diagonal tile

    // cross-quad row reduction (once, off the per-step critical path)
    l_st += __shfl_xor(l_st, 16);
    l_st += __shfl_xor(l_st, 32);

    const float linv = 1.0f / l_st;
    ushort* orow = Og + (size_t)(bq + qt * 64 + wl) * 1024 + h * 64 + quad * 4;
#pragma unroll
    for (int db = 0; db < 4; ++db) {
        uint2 w;
        w.x = (uint)f2b(od[db][0] * linv) | ((uint)f2b(od[db][1] * linv) << 16);
        w.y = (uint)f2b(od[db][2] * linv) | ((uint)f2b(od[db][3] * linv) << 16);
        *(uint2*)(orow + db * 16) = w;
    }
}

extern "C" void kernel_launch(void* const* d_in, const int* in_sizes, int n_in,
                              void* d_out, int out_size, void* d_ws, size_t ws_size,
                              hipStream_t stream) {
    const float* x  = (const float*)d_in[0];
    const float* wq = (const float*)d_in[1];
    const float* wk = (const float*)d_in[2];
    const float* wv = (const float*)d_in[3];
    const float* wo = (const float*)d_in[4];
    const int* pos  = (const int*)d_in[5];

    const size_t NX = (size_t)4096 * 1024;
    const size_t NW = (size_t)1024 * 1024;

    ushort* q_ws  = (ushort*)d_ws;          // 8 MB each, 32 MiB total
    ushort* k_ws  = q_ws + NX;
    ushort* vt_ws = k_ws + NX;
    ushort* o_ws  = vt_ws + NX;
    // d_out (16 MB) doubles as bf16 scratch + rope table until the final GEMM
    ushort* xb  = (ushort*)d_out;           // 8 MB
    ushort* wqb = xb + NX;                  // 2 MB each
    ushort* wkb = wqb + NW;
    ushort* wvb = wkb + NW;
    float2* tab = (float2*)(wvb + NW);      // 512 KB

    cvt4_k<<<dim3(3840), 256, 0, stream>>>(x, wq, wk, wv, xb, wqb, wkb, wvb, pos, tab);
    gemm_qkv<<<dim3(768), 512, 0, stream>>>(xb, wqb, wkb, wvb, q_ws, k_ws, vt_ws, tab);
    attn_k<<<dim3(1024), 256, 0, stream>>>(q_ws, k_ws, vt_ws, o_ws);
    cvt_k<<<dim3(512), 256, 0, stream>>>(wo, q_ws, (int)NW);   // q_ws dead now
    gemm_o<<<dim3(512), 512, 0, stream>>>(o_ws, q_ws, (float*)d_out);
}

// Round 12
// 179.385 us; speedup vs baseline: 2.1603x; 1.0314x over previous
//
#include <hip/hip_runtime.h>

typedef __attribute__((ext_vector_type(8))) short short8;
typedef __attribute__((ext_vector_type(4))) short short4v;
typedef __attribute__((ext_vector_type(4))) float floatx4;

__device__ inline ushort f2b(float f) {
    union { uint i; float f; } c; c.f = f;
    uint i = c.i;
    uint r = (i + 0x7FFFu + ((i >> 16) & 1u)) >> 16;
    return (ushort)r;
}

__device__ __forceinline__ void load_lds16(const ushort* g, ushort* l) {
    __builtin_amdgcn_global_load_lds((const __attribute__((address_space(1))) void*)g,
                                     (__attribute__((address_space(3))) void*)l, 16, 0, 0);
}

// Fused fp32->bf16 conversion of x, wq, wk, wv + RoPE cos/sin table (one launch).
__global__ __launch_bounds__(256) void cvt4_k(const float* __restrict__ x,
                                              const float* __restrict__ wq,
                                              const float* __restrict__ wk,
                                              const float* __restrict__ wv,
                                              ushort* __restrict__ xb,
                                              ushort* __restrict__ wqb,
                                              ushort* __restrict__ wkb,
                                              ushort* __restrict__ wvb,
                                              const int* __restrict__ pos,
                                              float2* __restrict__ tab) {
    const int blk = blockIdx.x;
    if (blk >= 3584) {
        const int idx = (blk - 3584) * 256 + threadIdx.x;   // 0..65535
        const int s = idx >> 5, fi = idx & 31;
        const float inv = exp2f(-(float)fi * 0.41524101186092557f);
        const float ang = (float)pos[s] * inv;
        float sn, cs;
        sincosf(ang, &sn, &cs);
        tab[idx] = make_float2(cs, sn);
        return;
    }
    const float* in; ushort* out; int base;
    if (blk < 2048)      { in = x;  out = xb;  base = blk; }
    else if (blk < 2560) { in = wq; out = wqb; base = blk - 2048; }
    else if (blk < 3072) { in = wk; out = wkb; base = blk - 2560; }
    else                 { in = wv; out = wvb; base = blk - 3072; }
    const int i = (base * 256 + threadIdx.x) * 8;
    float4 f0 = *(const float4*)(in + i);
    float4 f1 = *(const float4*)(in + i + 4);
    ushort u[8] = {f2b(f0.x), f2b(f0.y), f2b(f0.z), f2b(f0.w),
                   f2b(f1.x), f2b(f1.y), f2b(f1.z), f2b(f1.w)};
    *(uint4*)(out + i) = *(const uint4*)u;
}

// Fallback standalone wo conversion (used only when ws_size < 34 MB).
__global__ __launch_bounds__(256) void cvt_k(const float* __restrict__ in,
                                             ushort* __restrict__ out, int n) {
    const int i = (blockIdx.x * 256 + threadIdx.x) * 8;
    if (i >= n) return;
    float4 f0 = *(const float4*)(in + i);
    float4 f1 = *(const float4*)(in + i + 4);
    ushort u[8] = {f2b(f0.x), f2b(f0.y), f2b(f0.z), f2b(f0.w),
                   f2b(f1.x), f2b(f1.y), f2b(f1.z), f2b(f1.w)};
    *(uint4*)(out + i) = *(const uint4*)u;
}

// 128x128 GEMM body, K=1024, BK=32, EIGHT waves (2m x 4n of 64x32 each).
// Verified 2-phase skeleton: double-buffered LDS, one __syncthreads per K-iter.
template <bool OUTF32>
__device__ __forceinline__ void gemm_body8(ushort* As, ushort* Bs,   // [2][4096] each
                                           const ushort* __restrict__ A,
                                           const ushort* __restrict__ B,
                                           void* __restrict__ C,
                                           int N, int m0, int n0,
                                           bool doRope, const float2* __restrict__ tab,
                                           float oscale) {
    const int tid = threadIdx.x;            // 0..511
    const int wave = tid >> 6, lane = tid & 63;
    const int quad = lane >> 4, l16 = lane & 15;
    const int wm = (wave >> 2) * 64, wn = (wave & 3) * 32;

    floatx4 acc[4][2] = {};

    const int rA = tid >> 2, jgA = ((tid & 3) - (rA >> 1)) & 3;
    const ushort* ga = A + (size_t)(m0 + rA) * 1024 + jgA * 8;
    const ushort* gb = B + (size_t)(n0 + rA) * 1024 + jgA * 8;

    load_lds16(ga, As + tid * 8);
    load_lds16(gb, Bs + tid * 8);
    __syncthreads();

    for (int kt = 0; kt < 32; ++kt) {
        const int cur = kt & 1;
        if (kt + 1 < 32) {
            const int nb = (cur ^ 1) * 4096;
            load_lds16(ga + (kt + 1) * 32, As + nb + tid * 8);
            load_lds16(gb + (kt + 1) * 32, Bs + nb + tid * 8);
        }
        const ushort* as = As + cur * 4096;
        const ushort* bs = Bs + cur * 4096;
        short8 af[4], bf[2];
#pragma unroll
        for (int i = 0; i < 4; ++i) {
            const int ra = wm + i * 16 + l16;
            af[i] = *(const short8*)(as + ra * 32 + (((quad + (ra >> 1)) & 3) << 3));
        }
#pragma unroll
        for (int j = 0; j < 2; ++j) {
            const int rb = wn + j * 16 + l16;
            bf[j] = *(const short8*)(bs + rb * 32 + (((quad + (rb >> 1)) & 3) << 3));
        }
#pragma unroll
        for (int mi = 0; mi < 4; ++mi)
#pragma unroll
            for (int ni = 0; ni < 2; ++ni)
                acc[mi][ni] = __builtin_amdgcn_mfma_f32_16x16x32_bf16(af[mi], bf[ni], acc[mi][ni], 0, 0, 0);
        __syncthreads();
    }
#pragma unroll
    for (int mi = 0; mi < 4; ++mi) {
        const int row = m0 + wm + mi * 16 + quad * 4;
#pragma unroll
        for (int ni = 0; ni < 2; ++ni) {
            const int col = n0 + wn + ni * 16 + l16;
            const int fi = ((wn + ni * 16 + l16) & 63) >> 1;
#pragma unroll
            for (int r = 0; r < 4; ++r) {
                float v = acc[mi][ni][r];
                if (doRope) {
                    const float other = __shfl_xor(v, 1);
                    const float2 cs = tab[((row + r) & 2047) * 32 + fi];
                    v = (col & 1) ? (other * cs.y + v * cs.x) : (v * cs.x - other * cs.y);
                }
                v *= oscale;
                if (OUTF32) ((float*)C)[(size_t)(row + r) * N + col] = v;
                else        ((ushort*)C)[(size_t)(row + r) * N + col] = f2b(v);
            }
        }
    }
}

// Fused Q/K/Vt GEMM: 768 blocks x 512 threads (8 waves). R7-verified.
__global__ __launch_bounds__(512) void gemm_qkv(const ushort* __restrict__ xb,
                                                const ushort* __restrict__ wqb,
                                                const ushort* __restrict__ wkb,
                                                const ushort* __restrict__ wvb,
                                                ushort* __restrict__ q,
                                                ushort* __restrict__ k,
                                                ushort* __restrict__ vt,
                                                const float2* __restrict__ tab) {
    __shared__ __align__(16) ushort As[8192], Bs[8192];
    const int blk = blockIdx.x;
    const int job = blk >> 8, r = blk & 255;
    const ushort *A, *B;
    ushort* C;
    int N, m0, n0;
    bool rope;
    float osc;
    if (job == 0)      { A = xb;  B = wqb; C = q;  N = 1024; m0 = (r >> 3) * 128; n0 = (r & 7) * 128; rope = true;  osc = 0.18033688011112042f; }
    else if (job == 1) { A = xb;  B = wkb; C = k;  N = 1024; m0 = (r >> 3) * 128; n0 = (r & 7) * 128; rope = true;  osc = 1.0f; }
    else               { A = wvb; B = xb;  C = vt; N = 4096; m0 = (r & 7) * 128;  n0 = (r >> 3) * 128; rope = false; osc = 1.0f; }
    gemm_body8<false>(As, Bs, A, B, C, N, m0, n0, rope, tab, osc);
}

// Output projection: C fp32 = O[4096][1024] * wo[1024][1024]^T.
// R11-verified: 128x64 tile, EIGHT waves, 512 blocks = 2/CU -> 16 waves/CU.
__global__ __launch_bounds__(512) void gemm_o(const ushort* __restrict__ A,
                                              const ushort* __restrict__ B,
                                              float* __restrict__ C) {
    __shared__ __align__(16) ushort As[8192];   // 2 bufs x 128 rows x 32 cols
    __shared__ __align__(16) ushort Bs[4096];   // 2 bufs x  64 rows x 32 cols

    const int blk = blockIdx.x;
    const int m0 = (blk >> 4) * 128, n0 = (blk & 15) * 64;

    const int tid = threadIdx.x;            // 0..511
    const int wave = tid >> 6, lane = tid & 63;
    const int quad = lane >> 4, l16 = lane & 15;
    const int wm = (wave >> 2) * 64, wn = (wave & 3) * 16;

    floatx4 acc[4] = {};

    const int rA = tid >> 2, jgA = ((tid & 3) - (rA >> 1)) & 3;
    const ushort* ga = A + (size_t)(m0 + rA) * 1024 + jgA * 8;
    const int rB = (tid & 255) >> 2, jgB = (((tid & 255) & 3) - (rB >> 1)) & 3;
    const ushort* gb = B + (size_t)(n0 + rB) * 1024 + jgB * 8;

    load_lds16(ga, As + tid * 8);
    if (tid < 256) load_lds16(gb, Bs + tid * 8);
    __syncthreads();

    for (int kt = 0; kt < 32; ++kt) {
        const int cur = kt & 1;
        if (kt + 1 < 32) {
            load_lds16(ga + (kt + 1) * 32, As + (cur ^ 1) * 4096 + tid * 8);
            if (tid < 256)
                load_lds16(gb + (kt + 1) * 32, Bs + (cur ^ 1) * 2048 + tid * 8);
        }
        const ushort* as = As + cur * 4096;
        const ushort* bs = Bs + cur * 2048;
        short8 af[4], bf;
#pragma unroll
        for (int i = 0; i < 4; ++i) {
            const int ra = wm + i * 16 + l16;
            af[i] = *(const short8*)(as + ra * 32 + (((quad + (ra >> 1)) & 3) << 3));
        }
        {
            const int rb = wn + l16;
            bf = *(const short8*)(bs + rb * 32 + (((quad + (rb >> 1)) & 3) << 3));
        }
#pragma unroll
        for (int mi = 0; mi < 4; ++mi)
            acc[mi] = __builtin_amdgcn_mfma_f32_16x16x32_bf16(af[mi], bf, acc[mi], 0, 0, 0);
        __syncthreads();
    }
#pragma unroll
    for (int mi = 0; mi < 4; ++mi) {
        const int row = m0 + wm + mi * 16 + quad * 4;
        const int col = n0 + wn + l16;
#pragma unroll
        for (int r = 0; r < 4; ++r)
            C[(size_t)(row + r) * 1024 + col] = acc[mi][r];
    }
}

// Causal flash attention (R11-verified structure) + optional wo-conversion
// tail. Blocks [0,1024): attention, balanced qt map, all co-resident (4/CU),
// diag tile peeled, deferred l-reduction. Blocks [1024, 1536) (merged path
// only): wo fp32->bf16 conversion, executed in the drain tail of the attn
// blocks -- removes the separate cvt_k launch. wob lives at d_ws+32MB (q_ws
// is LIVE during attn; old home was a race).
__global__ __launch_bounds__(256, 4) void attn_k(const ushort* __restrict__ Qg,
                                                 const ushort* __restrict__ Kg,
                                                 const ushort* __restrict__ Vtg,
                                                 ushort* __restrict__ Og,
                                                 const float* __restrict__ wo,
                                                 ushort* __restrict__ wob) {
    __shared__ __align__(16) ushort Ks[2][4096];   // [s][d] chunk-swizzled
    __shared__ __align__(16) ushort Vs[2][4096];   // [d][s] chunk-swizzled

    const int tid = threadIdx.x;
    const int blk = blockIdx.x;
    if (blk >= 1024) {                      // wo-conversion tail (merged path)
        const int i = ((blk - 1024) * 256 + tid) * 8;
        float4 f0 = *(const float4*)(wo + i);
        float4 f1 = *(const float4*)(wo + i + 4);
        ushort u[8] = {f2b(f0.x), f2b(f0.y), f2b(f0.z), f2b(f0.w),
                       f2b(f1.x), f2b(f1.y), f2b(f1.z), f2b(f1.w)};
        *(uint4*)(wob + i) = *(const uint4*)u;
        return;
    }
    const int wave = tid >> 6, lane = tid & 63;
    const int quad = lane >> 4, l16 = lane & 15;
    const int g = blk >> 8, rem = blk & 255;
    const int t = rem >> 5, bh = rem & 31;
    int qt;
    if (g == 0)      qt = 31 - t;
    else if (g == 1) qt = 23 - t;
    else if (g == 2) qt = t;
    else             qt = 8 + t;
    const int b = bh >> 4, h = bh & 15;
    const int bq = b * 2048;
    const int wl = wave * 16 + l16;                // q-row within 64-row tile
    const int nk = qt + 1, dt = nk - 1;

    const int cA = tid, cB = tid + 256;
    const int sA = cA >> 3, jA = ((cA & 7) - sA) & 7;
    const int sB = cB >> 3, jB = ((cB & 7) - sB) & 7;
    const ushort* kgA = Kg + (size_t)(bq + sA) * 1024 + h * 64 + jA * 8;
    const ushort* kgB = Kg + (size_t)(bq + sB) * 1024 + h * 64 + jB * 8;
    const ushort* vgA = Vtg + (size_t)(h * 64 + sA) * 4096 + bq + jA * 8;
    const ushort* vgB = Vtg + (size_t)(h * 64 + sB) * 4096 + bq + jB * 8;

    // kt-invariant LDS read offsets (ushort units)
    const int kb0 = l16 * 64 + (((quad + l16) & 7) << 3);
    const int kb1 = l16 * 64 + (((quad + 4 + l16) & 7) << 3);
    int vbs[4];
#pragma unroll
    for (int cb = 0; cb < 4; ++cb)
        vbs[cb] = l16 * 64 + (((cb * 2 + (quad >> 1) + l16) & 7) << 3) + (quad & 1) * 4;

    const ushort* qrow = Qg + (size_t)(bq + qt * 64 + wl) * 1024 + h * 64 + quad * 8;
    const short8 qf0 = *(const short8*)qrow;
    const short8 qf1 = *(const short8*)(qrow + 32);

    floatx4 od[4] = {};
    float l_st = 0.0f;                      // per-lane partial; shfl-reduced at end

    load_lds16(kgA, &Ks[0][cA * 8]);
    load_lds16(kgB, &Ks[0][cB * 8]);
    load_lds16(vgA, &Vs[0][cA * 8]);
    load_lds16(vgB, &Vs[0][cB * 8]);
    __syncthreads();

    const ushort* kgA2 = kgA + 65536;
    const ushort* kgB2 = kgB + 65536;
    const ushort* vgA2 = vgA + 64;
    const ushort* vgB2 = vgB + 64;

    auto step = [&](int kt, bool diag, bool pref) {
        const int cur = kt & 1;
        if (pref) {
            const int nxt = cur ^ 1;
            load_lds16(kgA2, &Ks[nxt][cA * 8]);
            load_lds16(kgB2, &Ks[nxt][cB * 8]);
            load_lds16(vgA2, &Vs[nxt][cA * 8]);
            load_lds16(vgB2, &Vs[nxt][cB * 8]);
            kgA2 += 65536; kgB2 += 65536; vgA2 += 64; vgB2 += 64;
        }
        const ushort* kc = &Ks[cur][0];
        const ushort* vc = &Vs[cur][0];

        // S^T = K Q^T  (Q pre-scaled, st already in log2 domain)
        floatx4 st[4];
        __builtin_amdgcn_s_setprio(1);
#pragma unroll
        for (int cb = 0; cb < 4; ++cb) {
            short8 kf0 = *(const short8*)(kc + kb0 + cb * 1024);
            short8 kf1 = *(const short8*)(kc + kb1 + cb * 1024);
            floatx4 z = {};
            z = __builtin_amdgcn_mfma_f32_16x16x32_bf16(kf0, qf0, z, 0, 0, 0);
            z = __builtin_amdgcn_mfma_f32_16x16x32_bf16(kf1, qf1, z, 0, 0, 0);
            st[cb] = z;
        }
        __builtin_amdgcn_s_setprio(0);

        float pv[4][4];
        float sum = 0.0f;
#pragma unroll
        for (int cb = 0; cb < 4; ++cb) {
            const int scb = cb * 16 + quad * 4;
#pragma unroll
            for (int r = 0; r < 4; ++r) {
                float e = __builtin_amdgcn_exp2f(st[cb][r]);   // raw v_exp_f32
                if (diag && (scb + r > wl)) e = 0.0f;
                pv[cb][r] = e;
                sum += e;
            }
        }
        l_st += sum;                        // lane partial; cross-quad shfl deferred

        short4v pb[4];
#pragma unroll
        for (int cb = 0; cb < 4; ++cb) {
            uint lo_, hi_;
            asm("v_cvt_pk_bf16_f32 %0, %1, %2" : "=v"(lo_) : "v"(pv[cb][0]), "v"(pv[cb][1]));
            asm("v_cvt_pk_bf16_f32 %0, %1, %2" : "=v"(hi_) : "v"(pv[cb][2]), "v"(pv[cb][3]));
            union { uint u[2]; short4v s; } cvu;
            cvu.u[0] = lo_; cvu.u[1] = hi_;
            pb[cb] = cvu.s;
        }

        __builtin_amdgcn_s_setprio(1);
#pragma unroll
        for (int db = 0; db < 4; ++db) {
#pragma unroll
            for (int cb = 0; cb < 4; ++cb) {
                short4v vf = *(const short4v*)(vc + vbs[cb] + db * 1024);
                od[db] = __builtin_amdgcn_mfma_f32_16x16x16bf16_1k(vf, pb[cb], od[db], 0, 0, 0);
            }
        }
        __builtin_amdgcn_s_setprio(0);
        if (pref) __syncthreads();   // protect buffer reuse; last iter skips
    };

    for (int kt = 0; kt < dt; ++kt) step(kt, false, true);   // maskless main loop
    step(dt, true, false);                                    // peeled diagonal tile

    // cross-quad row reduction (once, off the per-step critical path)
    l_st += __shfl_xor(l_st, 16);
    l_st += __shfl_xor(l_st, 32);

    const float linv = 1.0f / l_st;
    ushort* orow = Og + (size_t)(bq + qt * 64 + wl) * 1024 + h * 64 + quad * 4;
#pragma unroll
    for (int db = 0; db < 4; ++db) {
        uint2 w;
        w.x = (uint)f2b(od[db][0] * linv) | ((uint)f2b(od[db][1] * linv) << 16);
        w.y = (uint)f2b(od[db][2] * linv) | ((uint)f2b(od[db][3] * linv) << 16);
        *(uint2*)(orow + db * 16) = w;
    }
}

extern "C" void kernel_launch(void* const* d_in, const int* in_sizes, int n_in,
                              void* d_out, int out_size, void* d_ws, size_t ws_size,
                              hipStream_t stream) {
    const float* x  = (const float*)d_in[0];
    const float* wq = (const float*)d_in[1];
    const float* wk = (const float*)d_in[2];
    const float* wv = (const float*)d_in[3];
    const float* wo = (const float*)d_in[4];
    const int* pos  = (const int*)d_in[5];

    const size_t NX = (size_t)4096 * 1024;
    const size_t NW = (size_t)1024 * 1024;

    ushort* q_ws  = (ushort*)d_ws;          // 8 MB each, 32 MiB base usage
    ushort* k_ws  = q_ws + NX;
    ushort* vt_ws = k_ws + NX;
    ushort* o_ws  = vt_ws + NX;
    // d_out (16 MB) doubles as bf16 scratch + rope table until the final GEMM
    ushort* xb  = (ushort*)d_out;           // 8 MB
    ushort* wqb = xb + NX;                  // 2 MB each
    ushort* wkb = wqb + NW;
    ushort* wvb = wkb + NW;
    float2* tab = (float2*)(wvb + NW);      // 512 KB

    // Merged path needs 2 MB extra workspace for wob (q_ws is LIVE during attn).
    const bool merged = ws_size >= (4 * NX + NW) * sizeof(ushort);
    ushort* wob = merged ? (o_ws + NX) : q_ws;   // d_ws+32MB, or fallback q_ws

    cvt4_k<<<dim3(3840), 256, 0, stream>>>(x, wq, wk, wv, xb, wqb, wkb, wvb, pos, tab);
    gemm_qkv<<<dim3(768), 512, 0, stream>>>(xb, wqb, wkb, wvb, q_ws, k_ws, vt_ws, tab);
    attn_k<<<dim3(merged ? 1536 : 1024), 256, 0, stream>>>(q_ws, k_ws, vt_ws, o_ws, wo, wob);
    if (!merged)
        cvt_k<<<dim3(512), 256, 0, stream>>>(wo, q_ws, (int)NW);   // q_ws dead now
    gemm_o<<<dim3(512), 512, 0, stream>>>(o_ws, wob, (float*)d_out);
}

// Round 13
// 177.976 us; speedup vs baseline: 2.1774x; 1.0079x over previous
//
#include <hip/hip_runtime.h>

typedef __attribute__((ext_vector_type(8))) short short8;
typedef __attribute__((ext_vector_type(4))) short short4v;
typedef __attribute__((ext_vector_type(4))) float floatx4;

__device__ inline ushort f2b(float f) {
    union { uint i; float f; } c; c.f = f;
    uint i = c.i;
    uint r = (i + 0x7FFFu + ((i >> 16) & 1u)) >> 16;
    return (ushort)r;
}

__device__ __forceinline__ void load_lds16(const ushort* g, ushort* l) {
    __builtin_amdgcn_global_load_lds((const __attribute__((address_space(1))) void*)g,
                                     (__attribute__((address_space(3))) void*)l, 16, 0, 0);
}

// Fused fp32->bf16 conversion of x, wq, wk, wv + RoPE cos/sin table (one launch).
__global__ __launch_bounds__(256) void cvt4_k(const float* __restrict__ x,
                                              const float* __restrict__ wq,
                                              const float* __restrict__ wk,
                                              const float* __restrict__ wv,
                                              ushort* __restrict__ xb,
                                              ushort* __restrict__ wqb,
                                              ushort* __restrict__ wkb,
                                              ushort* __restrict__ wvb,
                                              const int* __restrict__ pos,
                                              float2* __restrict__ tab) {
    const int blk = blockIdx.x;
    if (blk >= 3584) {
        const int idx = (blk - 3584) * 256 + threadIdx.x;   // 0..65535
        const int s = idx >> 5, fi = idx & 31;
        const float inv = exp2f(-(float)fi * 0.41524101186092557f);
        const float ang = (float)pos[s] * inv;
        float sn, cs;
        sincosf(ang, &sn, &cs);
        tab[idx] = make_float2(cs, sn);
        return;
    }
    const float* in; ushort* out; int base;
    if (blk < 2048)      { in = x;  out = xb;  base = blk; }
    else if (blk < 2560) { in = wq; out = wqb; base = blk - 2048; }
    else if (blk < 3072) { in = wk; out = wkb; base = blk - 2560; }
    else                 { in = wv; out = wvb; base = blk - 3072; }
    const int i = (base * 256 + threadIdx.x) * 8;
    float4 f0 = *(const float4*)(in + i);
    float4 f1 = *(const float4*)(in + i + 4);
    ushort u[8] = {f2b(f0.x), f2b(f0.y), f2b(f0.z), f2b(f0.w),
                   f2b(f1.x), f2b(f1.y), f2b(f1.z), f2b(f1.w)};
    *(uint4*)(out + i) = *(const uint4*)u;
}

// Fallback standalone wo conversion (used only when ws_size < 34 MB).
__global__ __launch_bounds__(256) void cvt_k(const float* __restrict__ in,
                                             ushort* __restrict__ out, int n) {
    const int i = (blockIdx.x * 256 + threadIdx.x) * 8;
    if (i >= n) return;
    float4 f0 = *(const float4*)(in + i);
    float4 f1 = *(const float4*)(in + i + 4);
    ushort u[8] = {f2b(f0.x), f2b(f0.y), f2b(f0.z), f2b(f0.w),
                   f2b(f1.x), f2b(f1.y), f2b(f1.z), f2b(f1.w)};
    *(uint4*)(out + i) = *(const uint4*)u;
}

// 128x128 GEMM body, K=1024, BK=32, EIGHT waves (2m x 4n of 64x32 each).
// Verified 2-phase skeleton: double-buffered LDS, one __syncthreads per K-iter.
template <bool OUTF32>
__device__ __forceinline__ void gemm_body8(ushort* As, ushort* Bs,   // [2][4096] each
                                           const ushort* __restrict__ A,
                                           const ushort* __restrict__ B,
                                           void* __restrict__ C,
                                           int N, int m0, int n0,
                                           bool doRope, const float2* __restrict__ tab,
                                           float oscale) {
    const int tid = threadIdx.x;            // 0..511
    const int wave = tid >> 6, lane = tid & 63;
    const int quad = lane >> 4, l16 = lane & 15;
    const int wm = (wave >> 2) * 64, wn = (wave & 3) * 32;

    floatx4 acc[4][2] = {};

    const int rA = tid >> 2, jgA = ((tid & 3) - (rA >> 1)) & 3;
    const ushort* ga = A + (size_t)(m0 + rA) * 1024 + jgA * 8;
    const ushort* gb = B + (size_t)(n0 + rA) * 1024 + jgA * 8;

    load_lds16(ga, As + tid * 8);
    load_lds16(gb, Bs + tid * 8);
    __syncthreads();

    for (int kt = 0; kt < 32; ++kt) {
        const int cur = kt & 1;
        if (kt + 1 < 32) {
            const int nb = (cur ^ 1) * 4096;
            load_lds16(ga + (kt + 1) * 32, As + nb + tid * 8);
            load_lds16(gb + (kt + 1) * 32, Bs + nb + tid * 8);
        }
        const ushort* as = As + cur * 4096;
        const ushort* bs = Bs + cur * 4096;
        short8 af[4], bf[2];
#pragma unroll
        for (int i = 0; i < 4; ++i) {
            const int ra = wm + i * 16 + l16;
            af[i] = *(const short8*)(as + ra * 32 + (((quad + (ra >> 1)) & 3) << 3));
        }
#pragma unroll
        for (int j = 0; j < 2; ++j) {
            const int rb = wn + j * 16 + l16;
            bf[j] = *(const short8*)(bs + rb * 32 + (((quad + (rb >> 1)) & 3) << 3));
        }
#pragma unroll
        for (int mi = 0; mi < 4; ++mi)
#pragma unroll
            for (int ni = 0; ni < 2; ++ni)
                acc[mi][ni] = __builtin_amdgcn_mfma_f32_16x16x32_bf16(af[mi], bf[ni], acc[mi][ni], 0, 0, 0);
        __syncthreads();
    }
#pragma unroll
    for (int mi = 0; mi < 4; ++mi) {
        const int row = m0 + wm + mi * 16 + quad * 4;
#pragma unroll
        for (int ni = 0; ni < 2; ++ni) {
            const int col = n0 + wn + ni * 16 + l16;
            const int fi = ((wn + ni * 16 + l16) & 63) >> 1;
#pragma unroll
            for (int r = 0; r < 4; ++r) {
                float v = acc[mi][ni][r];
                if (doRope) {
                    const float other = __shfl_xor(v, 1);
                    const float2 cs = tab[((row + r) & 2047) * 32 + fi];
                    v = (col & 1) ? (other * cs.y + v * cs.x) : (v * cs.x - other * cs.y);
                }
                v *= oscale;
                if (OUTF32) ((float*)C)[(size_t)(row + r) * N + col] = v;
                else        ((ushort*)C)[(size_t)(row + r) * N + col] = f2b(v);
            }
        }
    }
}

// Fused Q/K/Vt GEMM: 768 blocks x 512 threads (8 waves). R7-verified.
__global__ __launch_bounds__(512) void gemm_qkv(const ushort* __restrict__ xb,
                                                const ushort* __restrict__ wqb,
                                                const ushort* __restrict__ wkb,
                                                const ushort* __restrict__ wvb,
                                                ushort* __restrict__ q,
                                                ushort* __restrict__ k,
                                                ushort* __restrict__ vt,
                                                const float2* __restrict__ tab) {
    __shared__ __align__(16) ushort As[8192], Bs[8192];
    const int blk = blockIdx.x;
    const int job = blk >> 8, r = blk & 255;
    const ushort *A, *B;
    ushort* C;
    int N, m0, n0;
    bool rope;
    float osc;
    if (job == 0)      { A = xb;  B = wqb; C = q;  N = 1024; m0 = (r >> 3) * 128; n0 = (r & 7) * 128; rope = true;  osc = 0.18033688011112042f; }
    else if (job == 1) { A = xb;  B = wkb; C = k;  N = 1024; m0 = (r >> 3) * 128; n0 = (r & 7) * 128; rope = true;  osc = 1.0f; }
    else               { A = wvb; B = xb;  C = vt; N = 4096; m0 = (r & 7) * 128;  n0 = (r >> 3) * 128; rope = false; osc = 1.0f; }
    gemm_body8<false>(As, Bs, A, B, C, N, m0, n0, rope, tab, osc);
}

// Output projection: C fp32 = O[4096][1024] * wo[1024][1024]^T.
// R11-verified: 128x64 tile, EIGHT waves, 512 blocks = 2/CU -> 16 waves/CU.
__global__ __launch_bounds__(512) void gemm_o(const ushort* __restrict__ A,
                                              const ushort* __restrict__ B,
                                              float* __restrict__ C) {
    __shared__ __align__(16) ushort As[8192];   // 2 bufs x 128 rows x 32 cols
    __shared__ __align__(16) ushort Bs[4096];   // 2 bufs x  64 rows x 32 cols

    const int blk = blockIdx.x;
    const int m0 = (blk >> 4) * 128, n0 = (blk & 15) * 64;

    const int tid = threadIdx.x;            // 0..511
    const int wave = tid >> 6, lane = tid & 63;
    const int quad = lane >> 4, l16 = lane & 15;
    const int wm = (wave >> 2) * 64, wn = (wave & 3) * 16;

    floatx4 acc[4] = {};

    const int rA = tid >> 2, jgA = ((tid & 3) - (rA >> 1)) & 3;
    const ushort* ga = A + (size_t)(m0 + rA) * 1024 + jgA * 8;
    const int rB = (tid & 255) >> 2, jgB = (((tid & 255) & 3) - (rB >> 1)) & 3;
    const ushort* gb = B + (size_t)(n0 + rB) * 1024 + jgB * 8;

    load_lds16(ga, As + tid * 8);
    if (tid < 256) load_lds16(gb, Bs + tid * 8);
    __syncthreads();

    for (int kt = 0; kt < 32; ++kt) {
        const int cur = kt & 1;
        if (kt + 1 < 32) {
            load_lds16(ga + (kt + 1) * 32, As + (cur ^ 1) * 4096 + tid * 8);
            if (tid < 256)
                load_lds16(gb + (kt + 1) * 32, Bs + (cur ^ 1) * 2048 + tid * 8);
        }
        const ushort* as = As + cur * 4096;
        const ushort* bs = Bs + cur * 2048;
        short8 af[4], bf;
#pragma unroll
        for (int i = 0; i < 4; ++i) {
            const int ra = wm + i * 16 + l16;
            af[i] = *(const short8*)(as + ra * 32 + (((quad + (ra >> 1)) & 3) << 3));
        }
        {
            const int rb = wn + l16;
            bf = *(const short8*)(bs + rb * 32 + (((quad + (rb >> 1)) & 3) << 3));
        }
#pragma unroll
        for (int mi = 0; mi < 4; ++mi)
            acc[mi] = __builtin_amdgcn_mfma_f32_16x16x32_bf16(af[mi], bf, acc[mi], 0, 0, 0);
        __syncthreads();
    }
#pragma unroll
    for (int mi = 0; mi < 4; ++mi) {
        const int row = m0 + wm + mi * 16 + quad * 4;
        const int col = n0 + wn + l16;
#pragma unroll
        for (int r = 0; r < 4; ++r)
            C[(size_t)(row + r) * 1024 + col] = acc[mi][r];
    }
}

// Causal flash attention, PAIRED: 512 blocks x 512 threads. Waves 0-3 own
// q-tile qt_a in [16,31], waves 4-7 own qt_b in [0,15], SAME (b,h) -> the
// K/V stream is staged ONCE for both tiles (per-CU tile-stages 66 -> 49,
// exactly constant by the jIdx map: dispatcher pairs blocks c and c+256;
// jIdx = t<8 ? t : 23-t gives stage sum (32-j)+(32-(15-j)) = 49 per CU).
// Step count = nk_a (block-uniform); B-half compute is wave-uniform-guarded
// (no barrier inside). LDS unchanged (32 KB, shared tile). Step body per
// half is the R12-verified code. Blocks [512,768): wo fp32->bf16 conversion
// (merged path), co-resident with attn (3 blocks/CU = 96 KB LDS).
__global__ __launch_bounds__(512, 4) void attn_k(const ushort* __restrict__ Qg,
                                                 const ushort* __restrict__ Kg,
                                                 const ushort* __restrict__ Vtg,
                                                 ushort* __restrict__ Og,
                                                 const float* __restrict__ wo,
                                                 ushort* __restrict__ wob) {
    __shared__ __align__(16) ushort Ks[2][4096];   // [s][d] chunk-swizzled (shared)
    __shared__ __align__(16) ushort Vs[2][4096];   // [d][s] chunk-swizzled (shared)

    const int tid = threadIdx.x;            // 0..511
    const int blk = blockIdx.x;
    if (blk >= 512) {                       // wo-conversion tail (merged path)
        const int i = ((blk - 512) * 512 + tid) * 8;
        float4 f0 = *(const float4*)(wo + i);
        float4 f1 = *(const float4*)(wo + i + 4);
        ushort u[8] = {f2b(f0.x), f2b(f0.y), f2b(f0.z), f2b(f0.w),
                       f2b(f1.x), f2b(f1.y), f2b(f1.z), f2b(f1.w)};
        *(uint4*)(wob + i) = *(const uint4*)u;
        return;
    }
    const int wave = tid >> 6, lane = tid & 63;
    const int quad = lane >> 4, l16 = lane & 15;
    const int half = wave >> 2, wv = wave & 3;
    const int bh = blk & 31;
    const int t = blk >> 5;                 // 0..15
    const int jIdx = (t < 8) ? t : (23 - t);
    const int qt = half ? jIdx : (31 - jIdx);   // B-half: [0,15]; A-half: [16,31]
    const int nkA = 32 - jIdx;              // block step count (17..32)
    const int nkB = jIdx + 1;               // B-half active steps (1..16), <= 16 < nkA
    const int nk = half ? nkB : nkA;
    const int b = bh >> 4, h = bh & 15;
    const int bq = b * 2048;
    const int wl = wv * 16 + l16;           // q-row within this half's 64-row tile

    // staging: 512 threads, 1 K-chunk + 1 V-chunk each (512 chunks of 16B)
    const int sK = tid >> 3, jK = ((tid & 7) - sK) & 7;
    const ushort* kg = Kg + (size_t)(bq + sK) * 1024 + h * 64 + jK * 8;
    const ushort* vg = Vtg + (size_t)(h * 64 + sK) * 4096 + bq + jK * 8;

    // kt-invariant LDS read offsets (ushort units)
    const int kb0 = l16 * 64 + (((quad + l16) & 7) << 3);
    const int kb1 = l16 * 64 + (((quad + 4 + l16) & 7) << 3);
    int vbs[4];
#pragma unroll
    for (int cb = 0; cb < 4; ++cb)
        vbs[cb] = l16 * 64 + (((cb * 2 + (quad >> 1) + l16) & 7) << 3) + (quad & 1) * 4;

    const ushort* qrow = Qg + (size_t)(bq + qt * 64 + wl) * 1024 + h * 64 + quad * 8;
    const short8 qf0 = *(const short8*)qrow;
    const short8 qf1 = *(const short8*)(qrow + 32);

    floatx4 od[4] = {};
    float l_st = 0.0f;                      // per-lane partial; shfl-reduced at end

    load_lds16(kg, &Ks[0][tid * 8]);
    load_lds16(vg, &Vs[0][tid * 8]);
    __syncthreads();

    const ushort* kg2 = kg + 65536;
    const ushort* vg2 = vg + 64;

    for (int kt = 0; kt < nkA; ++kt) {
        const int cur = kt & 1;
        const bool pref = (kt + 1 < nkA);
        if (pref) {
            const int nxt = cur ^ 1;
            load_lds16(kg2, &Ks[nxt][tid * 8]);
            load_lds16(vg2, &Vs[nxt][tid * 8]);
            kg2 += 65536; vg2 += 64;
        }
        // wave-uniform activity guard: A-half always, B-half while kt < nkB
        if (!half || kt < nkB) {
            const bool diag = (kt == nk - 1);
            const ushort* kc = &Ks[cur][0];
            const ushort* vc = &Vs[cur][0];

            // S^T = K Q^T  (Q pre-scaled, st already in log2 domain)
            floatx4 st[4];
            __builtin_amdgcn_s_setprio(1);
#pragma unroll
            for (int cb = 0; cb < 4; ++cb) {
                short8 kf0 = *(const short8*)(kc + kb0 + cb * 1024);
                short8 kf1 = *(const short8*)(kc + kb1 + cb * 1024);
                floatx4 z = {};
                z = __builtin_amdgcn_mfma_f32_16x16x32_bf16(kf0, qf0, z, 0, 0, 0);
                z = __builtin_amdgcn_mfma_f32_16x16x32_bf16(kf1, qf1, z, 0, 0, 0);
                st[cb] = z;
            }
            __builtin_amdgcn_s_setprio(0);

            float pv[4][4];
            float sum = 0.0f;
#pragma unroll
            for (int cb = 0; cb < 4; ++cb) {
                const int scb = cb * 16 + quad * 4;
#pragma unroll
                for (int r = 0; r < 4; ++r) {
                    float e = __builtin_amdgcn_exp2f(st[cb][r]);   // raw v_exp_f32
                    if (diag && (scb + r > wl)) e = 0.0f;
                    pv[cb][r] = e;
                    sum += e;
                }
            }
            l_st += sum;                    // lane partial; cross-quad shfl deferred

            short4v pb[4];
#pragma unroll
            for (int cb = 0; cb < 4; ++cb) {
                uint lo_, hi_;
                asm("v_cvt_pk_bf16_f32 %0, %1, %2" : "=v"(lo_) : "v"(pv[cb][0]), "v"(pv[cb][1]));
                asm("v_cvt_pk_bf16_f32 %0, %1, %2" : "=v"(hi_) : "v"(pv[cb][2]), "v"(pv[cb][3]));
                union { uint u[2]; short4v s; } cvu;
                cvu.u[0] = lo_; cvu.u[1] = hi_;
                pb[cb] = cvu.s;
            }

            __builtin_amdgcn_s_setprio(1);
#pragma unroll
            for (int db = 0; db < 4; ++db) {
#pragma unroll
                for (int cb = 0; cb < 4; ++cb) {
                    short4v vf = *(const short4v*)(vc + vbs[cb] + db * 1024);
                    od[db] = __builtin_amdgcn_mfma_f32_16x16x16bf16_1k(vf, pb[cb], od[db], 0, 0, 0);
                }
            }
            __builtin_amdgcn_s_setprio(0);
        }
        if (pref) __syncthreads();          // block-uniform; last iter skips
    }

    // cross-quad row reduction (once, off the per-step critical path)
    l_st += __shfl_xor(l_st, 16);
    l_st += __shfl_xor(l_st, 32);

    const float linv = 1.0f / l_st;
    ushort* orow = Og + (size_t)(bq + qt * 64 + wl) * 1024 + h * 64 + quad * 4;
#pragma unroll
    for (int db = 0; db < 4; ++db) {
        uint2 w;
        w.x = (uint)f2b(od[db][0] * linv) | ((uint)f2b(od[db][1] * linv) << 16);
        w.y = (uint)f2b(od[db][2] * linv) | ((uint)f2b(od[db][3] * linv) << 16);
        *(uint2*)(orow + db * 16) = w;
    }
}

extern "C" void kernel_launch(void* const* d_in, const int* in_sizes, int n_in,
                              void* d_out, int out_size, void* d_ws, size_t ws_size,
                              hipStream_t stream) {
    const float* x  = (const float*)d_in[0];
    const float* wq = (const float*)d_in[1];
    const float* wk = (const float*)d_in[2];
    const float* wv = (const float*)d_in[3];
    const float* wo = (const float*)d_in[4];
    const int* pos  = (const int*)d_in[5];

    const size_t NX = (size_t)4096 * 1024;
    const size_t NW = (size_t)1024 * 1024;

    ushort* q_ws  = (ushort*)d_ws;          // 8 MB each, 32 MiB base usage
    ushort* k_ws  = q_ws + NX;
    ushort* vt_ws = k_ws + NX;
    ushort* o_ws  = vt_ws + NX;
    // d_out (16 MB) doubles as bf16 scratch + rope table until the final GEMM
    ushort* xb  = (ushort*)d_out;           // 8 MB
    ushort* wqb = xb + NX;                  // 2 MB each
    ushort* wkb = wqb + NW;
    ushort* wvb = wkb + NW;
    float2* tab = (float2*)(wvb + NW);      // 512 KB

    // Merged path needs 2 MB extra workspace for wob (q_ws is LIVE during attn).
    const bool merged = ws_size >= (4 * NX + NW) * sizeof(ushort);
    ushort* wob = merged ? (o_ws + NX) : q_ws;   // d_ws+32MB, or fallback q_ws

    cvt4_k<<<dim3(3840), 256, 0, stream>>>(x, wq, wk, wv, xb, wqb, wkb, wvb, pos, tab);
    gemm_qkv<<<dim3(768), 512, 0, stream>>>(xb, wqb, wkb, wvb, q_ws, k_ws, vt_ws, tab);
    attn_k<<<dim3(merged ? 768 : 512), 512, 0, stream>>>(q_ws, k_ws, vt_ws, o_ws, wo, wob);
    if (!merged)
        cvt_k<<<dim3(512), 256, 0, stream>>>(wo, q_ws, (int)NW);   // q_ws dead now
    gemm_o<<<dim3(512), 512, 0, stream>>>(o_ws, wob, (float*)d_out);
}